// Round 4
// baseline (3323.893 us; speedup 1.0000x reference)
//
#include <hip/hip_runtime.h>
#include <float.h>
#include <math.h>

#define NN 50000     // nodes
#define NE 200000    // edges
#define NB 128       // graphs

__device__ __forceinline__ float sgm(float x){ return 1.0f/(1.0f+expf(-x)); }

// ---------------- degree / batch counts ----------------
__global__ void k_deg(const int* __restrict__ dst, float* __restrict__ deg){
  int e = blockIdx.x*blockDim.x + threadIdx.x;
  if (e < NE) atomicAdd(&deg[dst[e]], 1.0f);
}
__global__ void k_cnt(const int* __restrict__ batch, int* __restrict__ cnt){
  int n = blockIdx.x*blockDim.x + threadIdx.x;
  if (n < NN) atomicAdd(&cnt[batch[n]], 1);
}
__global__ void k_scan(const int* __restrict__ cnt, int* __restrict__ startb){
  if (threadIdx.x==0 && blockIdx.x==0){
    int s=0;
    for (int b=0;b<NB;b++){ startb[b]=s; s+=cnt[b]; }
    startb[NB]=s;
  }
}

// ---------------- state init: relu(x @ lin0_w + b) ----------------
__global__ void k_init_state(const float* __restrict__ x, const float* __restrict__ w,
                             const float* __restrict__ b, float* __restrict__ state){
  int gid = blockIdx.x*blockDim.x + threadIdx.x;
  if (gid >= NN*32) return;
  int j = gid & 31;
  float xv = x[gid];
  float acc = b[j];
  #pragma unroll
  for (int h=0;h<32;h++) acc += __shfl(xv, h, 32) * w[h*32+j];
  state[gid] = fmaxf(acc, 0.0f);
}

// -------- GEMM chunk: we[e_local,1024] = relu(ea[e_base+e_local]@W1+b1)@W2 + b2 --------
// BM=64, BN=128, BK=64, 256 thr, thread tile 4x8. Writes CHUNK-LOCAL rows.
__global__ __launch_bounds__(256) void k_we_gemm(
    const float* __restrict__ ea, const float* __restrict__ w1, const float* __restrict__ b1,
    const float* __restrict__ w2, const float* __restrict__ b2, float* __restrict__ we,
    int e_base)
{
  __shared__ float As[64][64];    // [k][m]
  __shared__ float Bs[64][128];   // [k][n]
  __shared__ float sea[192];      // 64 edges x 3 attrs
  const int t   = threadIdx.x;
  const int m0  = blockIdx.x * 64;          // chunk-local edge base
  const int c0  = blockIdx.y * 128;
  if (t < 192) sea[t] = ea[(size_t)(e_base + m0)*3 + t];
  const int tx = t & 15;   // N dir
  const int ty = t >> 4;   // M dir
  float acc[4][8];
  #pragma unroll
  for (int i=0;i<4;i++)
    #pragma unroll
    for (int j=0;j<8;j++) acc[i][j]=0.0f;

  #pragma unroll
  for (int kt=0; kt<2; ++kt){
    const int k0 = kt*64;
    __syncthreads();
    // stage A with fused edge-MLP layer 1 (relu(ea@W1+b1))
    #pragma unroll
    for (int i=0;i<16;++i){
      int idx = t + i*256;          // 0..4095
      int k = idx >> 6;
      int m = idx & 63;
      int kk = k0 + k;
      float v = b1[kk]
              + sea[m*3+0]*w1[kk]
              + sea[m*3+1]*w1[128+kk]
              + sea[m*3+2]*w1[256+kk];
      As[k][m] = fmaxf(v, 0.0f);
    }
    // stage B
    #pragma unroll
    for (int i=0;i<8;++i){
      int idx = t + i*256;          // 0..2047
      int kr = idx >> 5;
      int cc = idx & 31;
      float4 v = *(const float4*)&w2[(size_t)(k0+kr)*1024 + c0 + cc*4];
      *(float4*)&Bs[kr][cc*4] = v;
    }
    __syncthreads();
    #pragma unroll 8
    for (int k=0;k<64;++k){
      float4 av  = *(const float4*)&As[k][ty*4];
      float4 bv0 = *(const float4*)&Bs[k][tx*4];
      float4 bv1 = *(const float4*)&Bs[k][64 + tx*4];
      float a_[4] = {av.x, av.y, av.z, av.w};
      float b_[8] = {bv0.x,bv0.y,bv0.z,bv0.w, bv1.x,bv1.y,bv1.z,bv1.w};
      #pragma unroll
      for (int i=0;i<4;i++)
        #pragma unroll
        for (int j=0;j<8;j++) acc[i][j] += a_[i]*b_[j];
    }
  }
  // epilogue: add bias, store (chunk-local)
  #pragma unroll
  for (int i=0;i<4;i++){
    size_t base = (size_t)(m0 + ty*4 + i)*1024 + c0;
    float4 o0, o1;
    o0.x = acc[i][0] + b2[c0 + tx*4 + 0];
    o0.y = acc[i][1] + b2[c0 + tx*4 + 1];
    o0.z = acc[i][2] + b2[c0 + tx*4 + 2];
    o0.w = acc[i][3] + b2[c0 + tx*4 + 3];
    o1.x = acc[i][4] + b2[c0 + 64 + tx*4 + 0];
    o1.y = acc[i][5] + b2[c0 + 64 + tx*4 + 1];
    o1.z = acc[i][6] + b2[c0 + 64 + tx*4 + 2];
    o1.w = acc[i][7] + b2[c0 + 64 + tx*4 + 3];
    *(float4*)&we[base + tx*4]      = o0;
    *(float4*)&we[base + 64 + tx*4] = o1;
  }
}

// ------- message + scatter for a chunk: agg[dst] += out[src] @ w_e[e] -------
__global__ void k_msg(const float* __restrict__ we, const float* __restrict__ state,
                      const int* __restrict__ src, const int* __restrict__ dst,
                      float* __restrict__ agg, int e_base, int e_count){
  int gid = blockIdx.x*blockDim.x + threadIdx.x;
  int el = gid >> 5;                 // chunk-local edge
  if (el >= e_count) return;
  int e = e_base + el;
  int o = gid & 31;
  int s = src[e], d = dst[e];
  float myo = state[s*32 + o];
  const float* w = we + (size_t)el*1024;
  float acc = 0.0f;
  #pragma unroll
  for (int h=0;h<32;++h) acc += __shfl(myo, h, 32) * w[h*32 + o];
  atomicAdd(&agg[d*32 + o], acc);
}

// ---------------- NNConv epilogue + GRU step (state == out == h) ----------------
__global__ __launch_bounds__(256) void k_node(
    float* __restrict__ state, const float* __restrict__ agg, const float* __restrict__ deg,
    const float* __restrict__ root_w, const float* __restrict__ conv_b,
    const float* __restrict__ wih, const float* __restrict__ whh,
    const float* __restrict__ bih, const float* __restrict__ bhh)
{
  __shared__ float s_root[1024], s_wih[3072], s_whh[3072];
  int t = threadIdx.x;
  for (int i=t;i<1024;i+=256) s_root[i] = root_w[i];
  for (int i=t;i<3072;i+=256){ s_wih[i]=wih[i]; s_whh[i]=whh[i]; }
  __syncthreads();
  int gid = blockIdx.x*256 + t;
  if (gid >= NN*32) return;
  int n = gid >> 5, j = gid & 31;
  float hv = state[gid];
  float dnm = fmaxf(deg[n], 1.0f);
  float acc = conv_b[j] + agg[gid]/dnm;
  #pragma unroll
  for (int h=0;h<32;h++) acc += __shfl(hv,h,32) * s_root[h*32+j];
  float m = fmaxf(acc, 0.0f);
  float xr = bih[j], xz = bih[32+j], xn = bih[64+j];
  #pragma unroll
  for (int h=0;h<32;h++){
    float mh = __shfl(m,h,32);
    xr += mh*s_wih[h*96+j];
    xz += mh*s_wih[h*96+32+j];
    xn += mh*s_wih[h*96+64+j];
  }
  float hr = bhh[j], hz = bhh[32+j], hn = bhh[64+j];
  #pragma unroll
  for (int h=0;h<32;h++){
    float hh2 = __shfl(hv,h,32);
    hr += hh2*s_whh[h*96+j];
    hz += hh2*s_whh[h*96+32+j];
    hn += hh2*s_whh[h*96+64+j];
  }
  float r  = sgm(xr+hr);
  float z  = sgm(xz+hz);
  float nc = tanhf(xn + r*hn);
  state[gid] = (1.0f - z)*nc + z*hv;
}

// ---------------- node_embed = state @ lin1_w + b ----------------
__global__ void k_embed(const float* __restrict__ state, const float* __restrict__ w,
                        const float* __restrict__ b, float* __restrict__ ne){
  int gid = blockIdx.x*blockDim.x + threadIdx.x;
  if (gid >= NN*32) return;
  int j = gid & 31;
  float sv = state[gid];
  float acc = b[j];
  #pragma unroll
  for (int h=0;h<32;h++) acc += __shfl(sv,h,32)*w[h*32+j];
  ne[gid] = acc;
}

// ---------------- Set2Set LSTM step (gate order i,f,g,o) ----------------
__global__ void k_lstm(const float* __restrict__ qstar, const float* __restrict__ hin,
                       float* __restrict__ hout, float* __restrict__ cs,
                       const float* __restrict__ wih, const float* __restrict__ whh,
                       const float* __restrict__ bih, const float* __restrict__ bhh){
  int gid = blockIdx.x*blockDim.x + threadIdx.x;
  if (gid >= NB*32) return;
  int b_ = gid >> 5, d = gid & 31;
  float gi = bih[d]    + bhh[d];
  float gf = bih[32+d] + bhh[32+d];
  float gg = bih[64+d] + bhh[64+d];
  float go = bih[96+d] + bhh[96+d];
  const float* q = &qstar[b_*64];
  #pragma unroll
  for (int k=0;k<64;k++){
    float qv = q[k];
    gi += qv*wih[k*128+d];
    gf += qv*wih[k*128+32+d];
    gg += qv*wih[k*128+64+d];
    go += qv*wih[k*128+96+d];
  }
  const float* hp = &hin[b_*32];
  #pragma unroll
  for (int k=0;k<32;k++){
    float hv = hp[k];
    gi += hv*whh[k*128+d];
    gf += hv*whh[k*128+32+d];
    gg += hv*whh[k*128+64+d];
    go += hv*whh[k*128+96+d];
  }
  float c_old = cs[gid];
  float cn = sgm(gf)*c_old + sgm(gi)*tanhf(gg);
  cs[gid] = cn;
  hout[gid] = sgm(go)*tanhf(cn);
}

// ---------------- Set2Set attention: one block per graph ----------------
__global__ __launch_bounds__(256) void k_attn(
    const float* __restrict__ ne, const float* __restrict__ hs,
    const int* __restrict__ startb, float* __restrict__ e_buf,
    float* __restrict__ qstar)
{
  __shared__ float s_red[8][32];
  __shared__ float s_wmax[4];
  __shared__ float s_asum;
  int b = blockIdx.x;
  int t = threadIdx.x;
  int g = t >> 5, j = t & 31;
  int s0 = startb[b], s1 = startb[b+1];
  if (t == 0) s_asum = 0.0f;
  float qv = hs[b*32 + j];
  // pass A: e_n = <ne[n], q>, track max
  float lmax = -FLT_MAX;
  for (int n = s0 + g; n < s1; n += 8){
    float p = ne[(size_t)n*32 + j] * qv;
    #pragma unroll
    for (int off=16; off; off>>=1) p += __shfl_xor(p, off, 32);
    if (j == 0) e_buf[n] = p;
    lmax = fmaxf(lmax, p);
  }
  #pragma unroll
  for (int off=32; off; off>>=1) lmax = fmaxf(lmax, __shfl_xor(lmax, off, 64));
  if ((t & 63) == 0) s_wmax[t >> 6] = lmax;
  __syncthreads();   // drains lane-0's e_buf stores (vmcnt(0) before s_barrier)
  float emax = fmaxf(fmaxf(s_wmax[0], s_wmax[1]), fmaxf(s_wmax[2], s_wmax[3]));
  // pass B: a = exp(e-emax); accumulate asum and sum a*ne
  float racc = 0.0f, asum = 0.0f;
  for (int n = s0 + g; n < s1; n += 8){
    float a = expf(e_buf[n] - emax);
    racc += a * ne[(size_t)n*32 + j];
    if (j == 0) asum += a;
  }
  if (j == 0) atomicAdd(&s_asum, asum);
  s_red[g][j] = racc;
  __syncthreads();
  if (t < 32){
    float r = 0.0f;
    #pragma unroll
    for (int g2=0; g2<8; g2++) r += s_red[g2][t];
    float as = s_asum;
    if (as == 0.0f) as = 1.0f;
    qstar[b*64 + t]      = hs[b*32 + t];
    qstar[b*64 + 32 + t] = r / as;
  }
}

// ---------------- graph head ----------------
__global__ void k_graph(const float* __restrict__ qstar, const float* __restrict__ w,
                        const float* __restrict__ b, float* __restrict__ ge){
  int gid = blockIdx.x*blockDim.x + threadIdx.x;
  if (gid >= NB*32) return;
  int b_ = gid >> 5, d = gid & 31;
  float acc = b[d];
  #pragma unroll
  for (int k=0;k<64;k++) acc += qstar[b_*64+k]*w[k*32+d];
  ge[gid] = acc;
}
__global__ void k_pred(const float* __restrict__ ge, const float* __restrict__ w,
                       const float* __restrict__ b, float* __restrict__ pred){
  int b_ = blockIdx.x*blockDim.x + threadIdx.x;
  if (b_ >= NB) return;
  float acc = b[0];
  #pragma unroll
  for (int d=0; d<32; d++) acc += ge[b_*32+d]*w[d];
  pred[b_] = acc;
}

extern "C" void kernel_launch(void* const* d_in, const int* in_sizes, int n_in,
                              void* d_out, int out_size, void* d_ws, size_t ws_size,
                              hipStream_t stream)
{
  const float* x        = (const float*)d_in[0];
  const float* ea       = (const float*)d_in[1];
  const float* lin0_w   = (const float*)d_in[2];
  const float* lin0_b   = (const float*)d_in[3];
  const float* nn1_w    = (const float*)d_in[4];
  const float* nn1_b    = (const float*)d_in[5];
  const float* nn2_w    = (const float*)d_in[6];
  const float* nn2_b    = (const float*)d_in[7];
  const float* root_w   = (const float*)d_in[8];
  const float* conv_b   = (const float*)d_in[9];
  const float* gru_wih  = (const float*)d_in[10];
  const float* gru_whh  = (const float*)d_in[11];
  const float* gru_bih  = (const float*)d_in[12];
  const float* gru_bhh  = (const float*)d_in[13];
  const float* lin1_w   = (const float*)d_in[14];
  const float* lin1_b   = (const float*)d_in[15];
  const float* lstm_wih = (const float*)d_in[16];
  const float* lstm_whh = (const float*)d_in[17];
  const float* lstm_bih = (const float*)d_in[18];
  const float* lstm_bhh = (const float*)d_in[19];
  const float* lin2_w   = (const float*)d_in[20];
  const float* lin2_b   = (const float*)d_in[21];
  const float* lin3_w   = (const float*)d_in[22];
  const float* lin3_b   = (const float*)d_in[23];
  const int*   eidx     = (const int*)d_in[24];
  const int*   batch    = (const int*)d_in[25];
  const int* src = eidx;
  const int* dst = eidx + NE;

  float* out  = (float*)d_out;
  float* pred = out;                 // [128]
  float* gemb = out + NB;            // [128,32]
  float* nemb = out + NB + NB*32;    // [N,32]

  // ---- workspace layout: small buffers FIRST, then w_e chunk buffer ----
  float* ws = (float*)d_ws;
  size_t cap = ws_size / sizeof(float);
  size_t off = 0;
  auto alloc = [&](size_t nelem){ float* p = ws + off; off += (nelem + 63) & ~(size_t)63; return p; };
  float* state = alloc((size_t)NN*32);     // out == h
  float* agg   = alloc((size_t)NN*32);
  float* e_buf = alloc(NN);
  int*   startb= (int*)alloc(256);
  float* zblk  = ws + off;                 // zero-initialized region below
  float* deg   = alloc(NN);
  int*   cnt   = (int*)alloc(NB);
  float* qstar = alloc(NB*64);
  float* hs0   = alloc(NB*32);
  float* hs1   = alloc(NB*32);
  float* cs    = alloc(NB*32);
  size_t zbytes = (size_t)((ws + off) - zblk) * sizeof(float);
  float* w_e   = ws + off;                 // chunk (or full) w_e buffer

  // chunk size in edges, multiple of 64, capped at NE
  size_t remain = (cap > off) ? (cap - off) : 0;
  size_t CH = (remain / 1024) & ~(size_t)63;
  if (CH > NE) CH = NE;
  if (CH < 64) CH = 64;                    // last-resort floor (ws assumed >= ~14 MB)
  const bool full = (CH >= (size_t)NE);

  hipMemsetAsync(zblk, 0, zbytes, stream);

  k_deg<<<(NE+255)/256, 256, 0, stream>>>(dst, deg);
  k_cnt<<<(NN+255)/256, 256, 0, stream>>>(batch, cnt);
  k_scan<<<1, 64, 0, stream>>>(cnt, startb);
  k_init_state<<<(NN*32)/256, 256, 0, stream>>>(x, lin0_w, lin0_b, state);

  if (full){
    // Path A: materialize all of w_e once, stream it 3x
    k_we_gemm<<<dim3(NE/64, 8), 256, 0, stream>>>(ea, nn1_w, nn1_b, nn2_w, nn2_b, w_e, 0);
    for (int it=0; it<3; ++it){
      hipMemsetAsync(agg, 0, (size_t)NN*32*sizeof(float), stream);
      k_msg<<<(NE*32)/256, 256, 0, stream>>>(w_e, state, src, dst, agg, 0, NE);
      k_node<<<(NN*32)/256, 256, 0, stream>>>(state, agg, deg, root_w, conv_b,
                                              gru_wih, gru_whh, gru_bih, gru_bhh);
    }
  } else {
    // Path B: recompute w_e in chunks each iteration (chunk stays L2/L3-resident)
    for (int it=0; it<3; ++it){
      hipMemsetAsync(agg, 0, (size_t)NN*32*sizeof(float), stream);
      for (size_t e0=0; e0<NE; e0+=CH){
        int c = (int)(((size_t)NE - e0 < CH) ? ((size_t)NE - e0) : CH);  // multiple of 64
        k_we_gemm<<<dim3(c/64, 8), 256, 0, stream>>>(ea, nn1_w, nn1_b, nn2_w, nn2_b, w_e, (int)e0);
        k_msg<<<(c*32)/256, 256, 0, stream>>>(w_e, state, src, dst, agg, (int)e0, c);
      }
      k_node<<<(NN*32)/256, 256, 0, stream>>>(state, agg, deg, root_w, conv_b,
                                              gru_wih, gru_whh, gru_bih, gru_bhh);
    }
  }
  k_embed<<<(NN*32)/256, 256, 0, stream>>>(state, lin1_w, lin1_b, nemb);

  float* hbuf[2] = {hs0, hs1};
  for (int t=0; t<3; ++t){
    float* hin  = hbuf[t & 1];
    float* hout = hbuf[1 - (t & 1)];
    k_lstm<<<(NB*32)/256, 256, 0, stream>>>(qstar, hin, hout, cs,
                                            lstm_wih, lstm_whh, lstm_bih, lstm_bhh);
    k_attn<<<NB, 256, 0, stream>>>(nemb, hout, startb, e_buf, qstar);
  }
  k_graph<<<(NB*32)/256, 256, 0, stream>>>(qstar, lin2_w, lin2_b, gemb);
  k_pred<<<1, NB, 0, stream>>>(gemb, lin3_w, lin3_b, pred);
}

// Round 6
// 2286.272 us; speedup vs baseline: 1.4538x; 1.4538x over previous
//
#include <hip/hip_runtime.h>
#include <float.h>
#include <math.h>

#define NN 50000     // nodes
#define NE 200000    // edges
#define NB 128       // graphs
#define LDA 136      // padded LDS row length in bf16 elems (272 B)

typedef short bf16x8 __attribute__((ext_vector_type(8)));
typedef float f32x4  __attribute__((ext_vector_type(4)));

__device__ __forceinline__ float sgm(float x){ return 1.0f/(1.0f+expf(-x)); }

__device__ __forceinline__ ushort f2bf(float f){   // RNE float->bf16 bits
  unsigned u = __float_as_uint(f);
  unsigned r = (u + 0x7FFFu + ((u >> 16) & 1u)) >> 16;
  return (ushort)r;
}

// ---------------- degree / batch counts ----------------
__global__ void k_deg(const int* __restrict__ dst, float* __restrict__ deg){
  int e = blockIdx.x*blockDim.x + threadIdx.x;
  if (e < NE) atomicAdd(&deg[dst[e]], 1.0f);
}
__global__ void k_cnt(const int* __restrict__ batch, int* __restrict__ cnt){
  int n = blockIdx.x*blockDim.x + threadIdx.x;
  if (n < NN) atomicAdd(&cnt[batch[n]], 1);
}
__global__ void k_scan(const int* __restrict__ cnt, int* __restrict__ startb){
  if (threadIdx.x==0 && blockIdx.x==0){
    int s=0;
    for (int b=0;b<NB;b++){ startb[b]=s; s+=cnt[b]; }
    startb[NB]=s;
  }
}

// ---------------- state init: relu(x @ lin0_w + b) ----------------
__global__ void k_init_state(const float* __restrict__ x, const float* __restrict__ w,
                             const float* __restrict__ b, float* __restrict__ state){
  int gid = blockIdx.x*blockDim.x + threadIdx.x;
  if (gid >= NN*32) return;
  int j = gid & 31;
  float xv = x[gid];
  float acc = b[j];
  #pragma unroll
  for (int h=0;h<32;h++) acc += __shfl(xv, h, 32) * w[h*32+j];
  state[gid] = fmaxf(acc, 0.0f);
}

// ---------------- one-time: w2t_bf[c][k] = bf16(w2[k][c]) ----------------
__global__ void k_w2t(const float* __restrict__ w2, ushort* __restrict__ w2t){
  int gid = blockIdx.x*256 + threadIdx.x;     // 131072
  if (gid >= 128*1024) return;
  int k = gid >> 10, c = gid & 1023;
  w2t[c*128 + k] = f2bf(w2[(size_t)k*1024 + c]);
}

// -------- MFMA GEMM chunk: we[m,1024] = relu(ea[e_base+m]@W1+b1)@W2 + b2 --------
// BM=128 edges, BN=128 cols, K=128 (full, no K-loop). 256 thr = 4 waves (2Mx2N),
// each wave 64x64 via 4x4 frags of mfma_f32_16x16x32_bf16.
__global__ __launch_bounds__(256) void k_we_mfma(
    const float* __restrict__ ea, const float* __restrict__ w1, const float* __restrict__ b1,
    const ushort* __restrict__ w2t, const float* __restrict__ b2,
    float* __restrict__ we, int e_base, int m_count)
{
  __shared__ __align__(16) ushort As[128*LDA];   // [m][k] bf16, padded
  __shared__ __align__(16) ushort Bs[128*LDA];   // [c][k] bf16, padded
  __shared__ float s_w1[384];
  __shared__ float s_b1[128];
  __shared__ float s_ea[384];

  const int t  = threadIdx.x;
  const int m0 = blockIdx.x * 128;          // chunk-local edge base
  const int c0 = blockIdx.y * 128;
  int mv = m_count - m0; if (mv > 128) mv = 128;   // valid edges in this tile

  // ---- phase 1: stage small fp32 + B tile ----
  for (int i=t; i<384; i+=256) s_w1[i] = w1[i];
  if (t < 128) s_b1[t] = b1[t];
  for (int i=t; i<384; i+=256)
    s_ea[i] = (i < mv*3) ? ea[(size_t)(e_base + m0)*3 + i] : 0.0f;
  #pragma unroll
  for (int i=0;i<8;++i){
    int idx = t + i*256;                    // 0..2047 : 128 rows x 16 segs(16B)
    int r = idx >> 4, s = idx & 15;
    uint4 v = *(const uint4*)&w2t[(size_t)(c0 + r)*128 + s*8];
    *(uint4*)((char*)Bs + r*272 + s*16) = v;
  }
  __syncthreads();

  // ---- phase 2: layer-1 MLP -> bf16 A tile ----
  {
    int m  = t >> 1;
    int kh = (t & 1) * 64;
    float a0 = s_ea[m*3+0], a1 = s_ea[m*3+1], a2 = s_ea[m*3+2];
    #pragma unroll
    for (int i=0;i<8;++i){
      bf16x8 pk;
      #pragma unroll
      for (int j=0;j<8;++j){
        int k = kh + i*8 + j;
        float v = s_b1[k] + a0*s_w1[k] + a1*s_w1[128+k] + a2*s_w1[256+k];
        pk[j] = (short)f2bf(fmaxf(v, 0.0f));
      }
      *(bf16x8*)&As[m*LDA + kh + i*8] = pk;
    }
  }
  __syncthreads();

  // ---- phase 3: MFMA ----
  const int w    = t >> 6;
  const int lane = t & 63;
  const int wr = w >> 1, wc = w & 1;
  const int l15 = lane & 15, l4 = lane >> 4;
  f32x4 acc[4][4];
  #pragma unroll
  for (int a=0;a<4;++a)
    #pragma unroll
    for (int b=0;b<4;++b) acc[a][b] = (f32x4){0.f,0.f,0.f,0.f};

  const ushort* pa = &As[(wr*64 + l15)*LDA + l4*8];
  const ushort* pb = &Bs[(wc*64 + l15)*LDA + l4*8];
  #pragma unroll
  for (int kk=0; kk<4; ++kk){
    bf16x8 af[4], bfr[4];
    #pragma unroll
    for (int f=0; f<4; ++f){
      af[f]  = *(const bf16x8*)&pa[f*16*LDA + kk*32];
      bfr[f] = *(const bf16x8*)&pb[f*16*LDA + kk*32];
    }
    #pragma unroll
    for (int mf=0; mf<4; ++mf)
      #pragma unroll
      for (int nf=0; nf<4; ++nf)
        acc[mf][nf] = __builtin_amdgcn_mfma_f32_16x16x32_bf16(af[mf], bfr[nf], acc[mf][nf], 0, 0, 0);
  }

  // ---- epilogue: +b2, fp32 store (C/D: col=lane&15, row=(lane>>4)*4+reg) ----
  #pragma unroll
  for (int nf=0; nf<4; ++nf){
    int c = c0 + wc*64 + nf*16 + l15;
    float b2v = b2[c];
    #pragma unroll
    for (int mf=0; mf<4; ++mf){
      int e = m0 + wr*64 + mf*16 + l4*4;
      #pragma unroll
      for (int r=0;r<4;++r){
        if (e + r < m_count)
          we[(size_t)(e+r)*1024 + c] = acc[mf][nf][r] + b2v;
      }
    }
  }
}

// ------- message + scatter for a chunk: agg[dst] += out[src] @ w_e[e] -------
__global__ void k_msg(const float* __restrict__ we, const float* __restrict__ state,
                      const int* __restrict__ src, const int* __restrict__ dst,
                      float* __restrict__ agg, int e_base, int e_count){
  int gid = blockIdx.x*blockDim.x + threadIdx.x;
  int el = gid >> 5;                 // chunk-local edge
  if (el >= e_count) return;
  int e = e_base + el;
  int o = gid & 31;
  int s = src[e], d = dst[e];
  float myo = state[s*32 + o];
  const float* w = we + (size_t)el*1024;
  float acc = 0.0f;
  #pragma unroll
  for (int h=0;h<32;++h) acc += __shfl(myo, h, 32) * w[h*32 + o];
  atomicAdd(&agg[d*32 + o], acc);
}

// ---------------- NNConv epilogue + GRU step (state == out == h) ----------------
__global__ __launch_bounds__(256) void k_node(
    float* __restrict__ state, const float* __restrict__ agg, const float* __restrict__ deg,
    const float* __restrict__ root_w, const float* __restrict__ conv_b,
    const float* __restrict__ wih, const float* __restrict__ whh,
    const float* __restrict__ bih, const float* __restrict__ bhh)
{
  __shared__ float s_root[1024], s_wih[3072], s_whh[3072];
  int t = threadIdx.x;
  for (int i=t;i<1024;i+=256) s_root[i] = root_w[i];
  for (int i=t;i<3072;i+=256){ s_wih[i]=wih[i]; s_whh[i]=whh[i]; }
  __syncthreads();
  int gid = blockIdx.x*256 + t;
  if (gid >= NN*32) return;
  int n = gid >> 5, j = gid & 31;
  float hv = state[gid];
  float dnm = fmaxf(deg[n], 1.0f);
  float acc = conv_b[j] + agg[gid]/dnm;
  #pragma unroll
  for (int h=0;h<32;h++) acc += __shfl(hv,h,32) * s_root[h*32+j];
  float m = fmaxf(acc, 0.0f);
  float xr = bih[j], xz = bih[32+j], xn = bih[64+j];
  #pragma unroll
  for (int h=0;h<32;h++){
    float mh = __shfl(m,h,32);
    xr += mh*s_wih[h*96+j];
    xz += mh*s_wih[h*96+32+j];
    xn += mh*s_wih[h*96+64+j];
  }
  float hr = bhh[j], hz = bhh[32+j], hn = bhh[64+j];
  #pragma unroll
  for (int h=0;h<32;h++){
    float hh2 = __shfl(hv,h,32);
    hr += hh2*s_whh[h*96+j];
    hz += hh2*s_whh[h*96+32+j];
    hn += hh2*s_whh[h*96+64+j];
  }
  float r  = sgm(xr+hr);
  float z  = sgm(xz+hz);
  float nc = tanhf(xn + r*hn);
  state[gid] = (1.0f - z)*nc + z*hv;
}

// ---------------- node_embed = state @ lin1_w + b ----------------
__global__ void k_embed(const float* __restrict__ state, const float* __restrict__ w,
                        const float* __restrict__ b, float* __restrict__ ne){
  int gid = blockIdx.x*blockDim.x + threadIdx.x;
  if (gid >= NN*32) return;
  int j = gid & 31;
  float sv = state[gid];
  float acc = b[j];
  #pragma unroll
  for (int h=0;h<32;h++) acc += __shfl(sv,h,32)*w[h*32+j];
  ne[gid] = acc;
}

// ---------------- Set2Set LSTM step (gate order i,f,g,o) ----------------
__global__ void k_lstm(const float* __restrict__ qstar, const float* __restrict__ hin,
                       float* __restrict__ hout, float* __restrict__ cs,
                       const float* __restrict__ wih, const float* __restrict__ whh,
                       const float* __restrict__ bih, const float* __restrict__ bhh){
  int gid = blockIdx.x*blockDim.x + threadIdx.x;
  if (gid >= NB*32) return;
  int b_ = gid >> 5, d = gid & 31;
  float gi = bih[d]    + bhh[d];
  float gf = bih[32+d] + bhh[32+d];
  float gg = bih[64+d] + bhh[64+d];
  float go = bih[96+d] + bhh[96+d];
  const float* q = &qstar[b_*64];
  #pragma unroll
  for (int k=0;k<64;k++){
    float qv = q[k];
    gi += qv*wih[k*128+d];
    gf += qv*wih[k*128+32+d];
    gg += qv*wih[k*128+64+d];
    go += qv*wih[k*128+96+d];
  }
  const float* hp = &hin[b_*32];
  #pragma unroll
  for (int k=0;k<32;k++){
    float hv = hp[k];
    gi += hv*whh[k*128+d];
    gf += hv*whh[k*128+32+d];
    gg += hv*whh[k*128+64+d];
    go += hv*whh[k*128+96+d];
  }
  float c_old = cs[gid];
  float cn = sgm(gf)*c_old + sgm(gi)*tanhf(gg);
  cs[gid] = cn;
  hout[gid] = sgm(go)*tanhf(cn);
}

// ---------------- Set2Set attention: one block per graph ----------------
__global__ __launch_bounds__(256) void k_attn(
    const float* __restrict__ ne, const float* __restrict__ hs,
    const int* __restrict__ startb, float* __restrict__ e_buf,
    float* __restrict__ qstar)
{
  __shared__ float s_red[8][32];
  __shared__ float s_wmax[4];
  __shared__ float s_asum;
  int b = blockIdx.x;
  int t = threadIdx.x;
  int g = t >> 5, j = t & 31;
  int s0 = startb[b], s1 = startb[b+1];
  if (t == 0) s_asum = 0.0f;
  float qv = hs[b*32 + j];
  float lmax = -FLT_MAX;
  for (int n = s0 + g; n < s1; n += 8){
    float p = ne[(size_t)n*32 + j] * qv;
    #pragma unroll
    for (int off=16; off; off>>=1) p += __shfl_xor(p, off, 32);
    if (j == 0) e_buf[n] = p;
    lmax = fmaxf(lmax, p);
  }
  #pragma unroll
  for (int off=32; off; off>>=1) lmax = fmaxf(lmax, __shfl_xor(lmax, off, 64));
  if ((t & 63) == 0) s_wmax[t >> 6] = lmax;
  __syncthreads();   // drains lane-0's e_buf stores (vmcnt(0) before s_barrier)
  float emax = fmaxf(fmaxf(s_wmax[0], s_wmax[1]), fmaxf(s_wmax[2], s_wmax[3]));
  float racc = 0.0f, asum = 0.0f;
  for (int n = s0 + g; n < s1; n += 8){
    float a = expf(e_buf[n] - emax);
    racc += a * ne[(size_t)n*32 + j];
    if (j == 0) asum += a;
  }
  if (j == 0) atomicAdd(&s_asum, asum);
  s_red[g][j] = racc;
  __syncthreads();
  if (t < 32){
    float r = 0.0f;
    #pragma unroll
    for (int g2=0; g2<8; g2++) r += s_red[g2][t];
    float as = s_asum;
    if (as == 0.0f) as = 1.0f;
    qstar[b*64 + t]      = hs[b*32 + t];
    qstar[b*64 + 32 + t] = r / as;
  }
}

// ---------------- graph head ----------------
__global__ void k_graph(const float* __restrict__ qstar, const float* __restrict__ w,
                        const float* __restrict__ b, float* __restrict__ ge){
  int gid = blockIdx.x*blockDim.x + threadIdx.x;
  if (gid >= NB*32) return;
  int b_ = gid >> 5, d = gid & 31;
  float acc = b[d];
  #pragma unroll
  for (int k=0;k<64;k++) acc += qstar[b_*64+k]*w[k*32+d];
  ge[gid] = acc;
}
__global__ void k_pred(const float* __restrict__ ge, const float* __restrict__ w,
                       const float* __restrict__ b, float* __restrict__ pred){
  int b_ = blockIdx.x*blockDim.x + threadIdx.x;
  if (b_ >= NB) return;
  float acc = b[0];
  #pragma unroll
  for (int d=0; d<32; d++) acc += ge[b_*32+d]*w[d];
  pred[b_] = acc;
}

extern "C" void kernel_launch(void* const* d_in, const int* in_sizes, int n_in,
                              void* d_out, int out_size, void* d_ws, size_t ws_size,
                              hipStream_t stream)
{
  const float* x        = (const float*)d_in[0];
  const float* ea       = (const float*)d_in[1];
  const float* lin0_w   = (const float*)d_in[2];
  const float* lin0_b   = (const float*)d_in[3];
  const float* nn1_w    = (const float*)d_in[4];
  const float* nn1_b    = (const float*)d_in[5];
  const float* nn2_w    = (const float*)d_in[6];
  const float* nn2_b    = (const float*)d_in[7];
  const float* root_w   = (const float*)d_in[8];
  const float* conv_b   = (const float*)d_in[9];
  const float* gru_wih  = (const float*)d_in[10];
  const float* gru_whh  = (const float*)d_in[11];
  const float* gru_bih  = (const float*)d_in[12];
  const float* gru_bhh  = (const float*)d_in[13];
  const float* lin1_w   = (const float*)d_in[14];
  const float* lin1_b   = (const float*)d_in[15];
  const float* lstm_wih = (const float*)d_in[16];
  const float* lstm_whh = (const float*)d_in[17];
  const float* lstm_bih = (const float*)d_in[18];
  const float* lstm_bhh = (const float*)d_in[19];
  const float* lin2_w   = (const float*)d_in[20];
  const float* lin2_b   = (const float*)d_in[21];
  const float* lin3_w   = (const float*)d_in[22];
  const float* lin3_b   = (const float*)d_in[23];
  const int*   eidx     = (const int*)d_in[24];
  const int*   batch    = (const int*)d_in[25];
  const int* src = eidx;
  const int* dst = eidx + NE;

  float* out  = (float*)d_out;
  float* pred = out;                 // [128]
  float* gemb = out + NB;            // [128,32]
  float* nemb = out + NB + NB*32;    // [N,32]

  // ---- workspace: small buffers FIRST, then w_e chunk buffer ----
  float* ws = (float*)d_ws;
  size_t cap = ws_size / sizeof(float);
  size_t off = 0;
  auto alloc = [&](size_t nelem){ float* p = ws + off; off += (nelem + 63) & ~(size_t)63; return p; };
  float*  state = alloc((size_t)NN*32);
  float*  agg   = alloc((size_t)NN*32);
  float*  e_buf = alloc(NN);
  int*    startb= (int*)alloc(256);
  ushort* w2t   = (ushort*)alloc(65536);   // 128x1024 bf16 (transposed [c][k])
  float*  zblk  = ws + off;                // zero-initialized region below
  float*  deg   = alloc(NN);
  int*    cnt   = (int*)alloc(NB);
  float*  qstar = alloc(NB*64);
  float*  hs0   = alloc(NB*32);
  float*  hs1   = alloc(NB*32);
  float*  cs    = alloc(NB*32);
  size_t zbytes = (size_t)((ws + off) - zblk) * sizeof(float);
  float*  w_e   = ws + off;                // chunk buffer

  size_t remain = (cap > off) ? (cap - off) : 0;
  size_t CH = (remain / 1024) & ~(size_t)127;  // edges per chunk, mult of 128
  if (CH > 49152) CH = 49152;                  // keep chunk (~201 MB) L3-resident
  if (CH < 128) CH = 128;

  hipMemsetAsync(zblk, 0, zbytes, stream);

  k_deg<<<(NE+255)/256, 256, 0, stream>>>(dst, deg);
  k_cnt<<<(NN+255)/256, 256, 0, stream>>>(batch, cnt);
  k_scan<<<1, 64, 0, stream>>>(cnt, startb);
  k_init_state<<<(NN*32)/256, 256, 0, stream>>>(x, lin0_w, lin0_b, state);
  k_w2t<<<512, 256, 0, stream>>>(nn2_w, w2t);

  for (int it=0; it<3; ++it){
    hipMemsetAsync(agg, 0, (size_t)NN*32*sizeof(float), stream);
    for (size_t e0=0; e0<NE; e0+=CH){
      int c = (int)(((size_t)NE - e0 < CH) ? ((size_t)NE - e0) : CH);
      k_we_mfma<<<dim3((c+127)/128, 8), 256, 0, stream>>>(ea, nn1_w, nn1_b, w2t, nn2_b,
                                                          w_e, (int)e0, c);
      k_msg<<<(c*32+255)/256, 256, 0, stream>>>(w_e, state, src, dst, agg, (int)e0, c);
    }
    k_node<<<(NN*32)/256, 256, 0, stream>>>(state, agg, deg, root_w, conv_b,
                                            gru_wih, gru_whh, gru_bih, gru_bhh);
  }
  k_embed<<<(NN*32)/256, 256, 0, stream>>>(state, lin1_w, lin1_b, nemb);

  float* hbuf[2] = {hs0, hs1};
  for (int t=0; t<3; ++t){
    float* hin  = hbuf[t & 1];
    float* hout = hbuf[1 - (t & 1)];
    k_lstm<<<(NB*32)/256, 256, 0, stream>>>(qstar, hin, hout, cs,
                                            lstm_wih, lstm_whh, lstm_bih, lstm_bhh);
    k_attn<<<NB, 256, 0, stream>>>(nemb, hout, startb, e_buf, qstar);
  }
  k_graph<<<(NB*32)/256, 256, 0, stream>>>(qstar, lin2_w, lin2_b, gemb);
  k_pred<<<1, NB, 0, stream>>>(gemb, lin3_w, lin3_b, pred);
}

// Round 7
// 1214.808 us; speedup vs baseline: 2.7361x; 1.8820x over previous
//
#include <hip/hip_runtime.h>
#include <float.h>
#include <math.h>

#define NN 50000     // nodes
#define NE 200000    // edges
#define NB 128       // graphs
#define BM 128       // edges per fused-message block

typedef short bf16x8 __attribute__((ext_vector_type(8)));
typedef float f32x4  __attribute__((ext_vector_type(4)));

__device__ __forceinline__ float sgm(float x){ return 1.0f/(1.0f+expf(-x)); }

__device__ __forceinline__ ushort f2bf(float f){   // RNE float->bf16 bits
  unsigned u = __float_as_uint(f);
  return (ushort)((u + 0x7FFFu + ((u >> 16) & 1u)) >> 16);
}
__device__ __forceinline__ float bf2f(ushort s){
  return __uint_as_float(((unsigned)s) << 16);
}

// ---------------- degree / batch counts ----------------
__global__ void k_deg(const int* __restrict__ dst, float* __restrict__ deg){
  int e = blockIdx.x*blockDim.x + threadIdx.x;
  if (e < NE) atomicAdd(&deg[dst[e]], 1.0f);
}
__global__ void k_cnt(const int* __restrict__ batch, int* __restrict__ cnt){
  int n = blockIdx.x*blockDim.x + threadIdx.x;
  if (n < NN) atomicAdd(&cnt[batch[n]], 1);
}
__global__ void k_scan(const int* __restrict__ cnt, int* __restrict__ startb){
  if (threadIdx.x==0 && blockIdx.x==0){
    int s=0;
    for (int b=0;b<NB;b++){ startb[b]=s; s+=cnt[b]; }
    startb[NB]=s;
  }
}

// ---------------- state init: relu(x @ lin0_w + b) ----------------
__global__ void k_init_state(const float* __restrict__ x, const float* __restrict__ w,
                             const float* __restrict__ b, float* __restrict__ state){
  int gid = blockIdx.x*blockDim.x + threadIdx.x;
  if (gid >= NN*32) return;
  int j = gid & 31;
  float xv = x[gid];
  float acc = b[j];
  #pragma unroll
  for (int h=0;h<32;h++) acc += __shfl(xv, h, 32) * w[h*32+j];
  state[gid] = fmaxf(acc, 0.0f);
}

// ---- one-time B-fragment pack: w2c[((k*2+n)*64+l)*8+j] = bf16(W2[k][h*32+o]),
//      h = (l>>4)*8+j, o = n*16+(l&15)  (lane-linear 16B loads in k_fused) ----
__global__ void k_w2c(const float* __restrict__ w2, ushort* __restrict__ w2c){
  int gid = blockIdx.x*256 + threadIdx.x;     // 131072
  if (gid >= 131072) return;
  int j = gid & 7, l = (gid >> 3) & 63, n = (gid >> 9) & 1, k = gid >> 10;
  int h = (l >> 4)*8 + j, o = n*16 + (l & 15);
  w2c[gid] = f2bf(w2[(size_t)k*1024 + h*32 + o]);
}

// -------- fused NNConv message: agg[dst[e]][o] += sum_{k,h} a_e[k]*x_src[e][h]*W2[k][h*32+o]
// BM=128 edges/block, 256 thr = 4 waves x 32 edges; MFMA 16x16x32 bf16 (layouts
// verified by round-6 pass). A generated on the fly: af = bf16(a[e][k] * xf[h]).
__global__ __launch_bounds__(256) void k_fused(
    const float* __restrict__ ea, const float* __restrict__ w1, const float* __restrict__ b1,
    const ushort* __restrict__ w2c, const float* __restrict__ state,
    const int* __restrict__ src, const int* __restrict__ dst,
    float* __restrict__ agg)
{
  __shared__ __align__(16) ushort aT[128][136];   // [k][e_local] bf16, pad 8
  __shared__ __align__(16) float  xs[128][36];    // [e_local][h] f32, pad 4
  __shared__ float s_w1[384], s_b1[128], s_ea[384];
  __shared__ int   s_src[128], s_dst[128];

  const int t   = threadIdx.x;
  const int e00 = blockIdx.x * BM;
  const int mv  = min(BM, NE - e00);

  // ---- phase 1: stage small inputs ----
  for (int i=t; i<384; i+=256) s_w1[i] = w1[i];
  if (t < 128) s_b1[t] = b1[t];
  for (int i=t; i<384; i+=256) s_ea[i] = (i < mv*3) ? ea[(size_t)e00*3 + i] : 0.0f;
  if (t < 128){
    bool v = t < mv;
    s_src[t] = v ? src[e00 + t] : 0;
    s_dst[t] = v ? dst[e00 + t] : 0;
  }
  __syncthreads();

  // ---- phase 2a: gather x_src (invalid edges -> 0, kills padded-a products) ----
  #pragma unroll
  for (int i=0; i<4; ++i){
    int idx = t + i*256;            // 0..1023 : 128 edges x 8 float4
    int el = idx >> 3, ch = idx & 7;
    float4 v = make_float4(0.f,0.f,0.f,0.f);
    if (el < mv) v = *(const float4*)&state[(size_t)s_src[el]*32 + ch*4];
    *(float4*)&xs[el][ch*4] = v;
  }
  // ---- phase 2b: a-gen: aT[k][e] = bf16(relu(ea[e]@W1 + b1)[k]) ----
  {
    int k = t & 127, half = t >> 7;
    float w0 = s_w1[k], w1_ = s_w1[128+k], w2_ = s_w1[256+k], bb = s_b1[k];
    #pragma unroll
    for (int e8=0; e8<8; ++e8){
      bf16x8 pk;
      #pragma unroll
      for (int jj=0; jj<8; ++jj){
        int el = half*64 + e8*8 + jj;
        float v = bb + s_ea[el*3]*w0 + s_ea[el*3+1]*w1_ + s_ea[el*3+2]*w2_;
        pk[jj] = (short)f2bf(fmaxf(v, 0.0f));
      }
      *(bf16x8*)&aT[k][half*64 + e8*8] = pk;
    }
  }
  __syncthreads();

  // ---- phase 3: K-loop (128 k-values), 4 MFMA/k/wave ----
  const int w    = t >> 6;
  const int lane = t & 63;
  const int l15  = lane & 15, l4 = lane >> 4;
  float xf[2][8];
  #pragma unroll
  for (int m=0; m<2; ++m)
    #pragma unroll
    for (int j=0; j<8; ++j) xf[m][j] = xs[w*32 + m*16 + l15][l4*8 + j];

  f32x4 acc[2][2];
  #pragma unroll
  for (int m=0; m<2; ++m)
    #pragma unroll
    for (int n=0; n<2; ++n) acc[m][n] = (f32x4){0.f,0.f,0.f,0.f};

  #pragma unroll 4
  for (int k=0; k<128; ++k){
    float a0 = bf2f(aT[k][w*32 + l15]);        // broadcast reads (conflict-free)
    float a1 = bf2f(aT[k][w*32 + 16 + l15]);
    bf16x8 b0 = *(const bf16x8*)&w2c[((size_t)k*128 + lane)*8];       // L2-hot, coalesced
    bf16x8 b1 = *(const bf16x8*)&w2c[((size_t)k*128 + 64 + lane)*8];
    bf16x8 a0f, a1f;
    #pragma unroll
    for (int p=0; p<4; ++p){                   // round-half-up bf16 pack
      unsigned u0 = __float_as_uint(a0*xf[0][2*p])   + 0x8000u;
      unsigned u1 = __float_as_uint(a0*xf[0][2*p+1]) + 0x8000u;
      ((unsigned*)&a0f)[p] = (u1 & 0xFFFF0000u) | (u0 >> 16);
      unsigned v0 = __float_as_uint(a1*xf[1][2*p])   + 0x8000u;
      unsigned v1 = __float_as_uint(a1*xf[1][2*p+1]) + 0x8000u;
      ((unsigned*)&a1f)[p] = (v1 & 0xFFFF0000u) | (v0 >> 16);
    }
    acc[0][0] = __builtin_amdgcn_mfma_f32_16x16x32_bf16(a0f, b0, acc[0][0], 0,0,0);
    acc[0][1] = __builtin_amdgcn_mfma_f32_16x16x32_bf16(a0f, b1, acc[0][1], 0,0,0);
    acc[1][0] = __builtin_amdgcn_mfma_f32_16x16x32_bf16(a1f, b0, acc[1][0], 0,0,0);
    acc[1][1] = __builtin_amdgcn_mfma_f32_16x16x32_bf16(a1f, b1, acc[1][1], 0,0,0);
  }

  // ---- epilogue: scatter (C/D: col=l&15, row=(l>>4)*4+r — verified) ----
  #pragma unroll
  for (int m=0; m<2; ++m)
    #pragma unroll
    for (int n=0; n<2; ++n)
      #pragma unroll
      for (int r=0; r<4; ++r){
        int el = w*32 + m*16 + l4*4 + r;
        if (e00 + el < NE)
          atomicAdd(&agg[(size_t)s_dst[el]*32 + n*16 + l15], acc[m][n][r]);
      }
}

// ---------------- NNConv epilogue + GRU step (state == out == h) ----------------
__global__ __launch_bounds__(256) void k_node(
    float* __restrict__ state, const float* __restrict__ agg, const float* __restrict__ deg,
    const float* __restrict__ root_w, const float* __restrict__ conv_b,
    const float* __restrict__ wih, const float* __restrict__ whh,
    const float* __restrict__ bih, const float* __restrict__ bhh)
{
  __shared__ float s_root[1024], s_wih[3072], s_whh[3072];
  int t = threadIdx.x;
  for (int i=t;i<1024;i+=256) s_root[i] = root_w[i];
  for (int i=t;i<3072;i+=256){ s_wih[i]=wih[i]; s_whh[i]=whh[i]; }
  __syncthreads();
  int gid = blockIdx.x*256 + t;
  if (gid >= NN*32) return;
  int n = gid >> 5, j = gid & 31;
  float hv = state[gid];
  float dnm = fmaxf(deg[n], 1.0f);
  float acc = conv_b[j] + agg[gid]/dnm;
  #pragma unroll
  for (int h=0;h<32;h++) acc += __shfl(hv,h,32) * s_root[h*32+j];
  float m = fmaxf(acc, 0.0f);
  float xr = bih[j], xz = bih[32+j], xn = bih[64+j];
  #pragma unroll
  for (int h=0;h<32;h++){
    float mh = __shfl(m,h,32);
    xr += mh*s_wih[h*96+j];
    xz += mh*s_wih[h*96+32+j];
    xn += mh*s_wih[h*96+64+j];
  }
  float hr = bhh[j], hz = bhh[32+j], hn = bhh[64+j];
  #pragma unroll
  for (int h=0;h<32;h++){
    float hh2 = __shfl(hv,h,32);
    hr += hh2*s_whh[h*96+j];
    hz += hh2*s_whh[h*96+32+j];
    hn += hh2*s_whh[h*96+64+j];
  }
  float r  = sgm(xr+hr);
  float z  = sgm(xz+hz);
  float nc = tanhf(xn + r*hn);
  state[gid] = (1.0f - z)*nc + z*hv;
}

// ---------------- node_embed = state @ lin1_w + b ----------------
__global__ void k_embed(const float* __restrict__ state, const float* __restrict__ w,
                        const float* __restrict__ b, float* __restrict__ ne){
  int gid = blockIdx.x*blockDim.x + threadIdx.x;
  if (gid >= NN*32) return;
  int j = gid & 31;
  float sv = state[gid];
  float acc = b[j];
  #pragma unroll
  for (int h=0;h<32;h++) acc += __shfl(sv,h,32)*w[h*32+j];
  ne[gid] = acc;
}

// ---------------- Set2Set LSTM step (gate order i,f,g,o) ----------------
__global__ void k_lstm(const float* __restrict__ qstar, const float* __restrict__ hin,
                       float* __restrict__ hout, float* __restrict__ cs,
                       const float* __restrict__ wih, const float* __restrict__ whh,
                       const float* __restrict__ bih, const float* __restrict__ bhh){
  int gid = blockIdx.x*blockDim.x + threadIdx.x;
  if (gid >= NB*32) return;
  int b_ = gid >> 5, d = gid & 31;
  float gi = bih[d]    + bhh[d];
  float gf = bih[32+d] + bhh[32+d];
  float gg = bih[64+d] + bhh[64+d];
  float go = bih[96+d] + bhh[96+d];
  const float* q = &qstar[b_*64];
  #pragma unroll
  for (int k=0;k<64;k++){
    float qv = q[k];
    gi += qv*wih[k*128+d];
    gf += qv*wih[k*128+32+d];
    gg += qv*wih[k*128+64+d];
    go += qv*wih[k*128+96+d];
  }
  const float* hp = &hin[b_*32];
  #pragma unroll
  for (int k=0;k<32;k++){
    float hv = hp[k];
    gi += hv*whh[k*128+d];
    gf += hv*whh[k*128+32+d];
    gg += hv*whh[k*128+64+d];
    go += hv*whh[k*128+96+d];
  }
  float c_old = cs[gid];
  float cn = sgm(gf)*c_old + sgm(gi)*tanhf(gg);
  cs[gid] = cn;
  hout[gid] = sgm(go)*tanhf(cn);
}

// ---------------- Set2Set attention: one block per graph ----------------
__global__ __launch_bounds__(256) void k_attn(
    const float* __restrict__ ne, const float* __restrict__ hs,
    const int* __restrict__ startb, float* __restrict__ e_buf,
    float* __restrict__ qstar)
{
  __shared__ float s_red[8][32];
  __shared__ float s_wmax[4];
  __shared__ float s_asum;
  int b = blockIdx.x;
  int t = threadIdx.x;
  int g = t >> 5, j = t & 31;
  int s0 = startb[b], s1 = startb[b+1];
  if (t == 0) s_asum = 0.0f;
  float qv = hs[b*32 + j];
  float lmax = -FLT_MAX;
  for (int n = s0 + g; n < s1; n += 8){
    float p = ne[(size_t)n*32 + j] * qv;
    #pragma unroll
    for (int off=16; off; off>>=1) p += __shfl_xor(p, off, 32);
    if (j == 0) e_buf[n] = p;
    lmax = fmaxf(lmax, p);
  }
  #pragma unroll
  for (int off=32; off; off>>=1) lmax = fmaxf(lmax, __shfl_xor(lmax, off, 64));
  if ((t & 63) == 0) s_wmax[t >> 6] = lmax;
  __syncthreads();   // drains lane-0's e_buf stores
  float emax = fmaxf(fmaxf(s_wmax[0], s_wmax[1]), fmaxf(s_wmax[2], s_wmax[3]));
  float racc = 0.0f, asum = 0.0f;
  for (int n = s0 + g; n < s1; n += 8){
    float a = expf(e_buf[n] - emax);
    racc += a * ne[(size_t)n*32 + j];
    if (j == 0) asum += a;
  }
  if (j == 0) atomicAdd(&s_asum, asum);
  s_red[g][j] = racc;
  __syncthreads();
  if (t < 32){
    float r = 0.0f;
    #pragma unroll
    for (int g2=0; g2<8; g2++) r += s_red[g2][t];
    float as = s_asum;
    if (as == 0.0f) as = 1.0f;
    qstar[b*64 + t]      = hs[b*32 + t];
    qstar[b*64 + 32 + t] = r / as;
  }
}

// ---------------- graph head ----------------
__global__ void k_graph(const float* __restrict__ qstar, const float* __restrict__ w,
                        const float* __restrict__ b, float* __restrict__ ge){
  int gid = blockIdx.x*blockDim.x + threadIdx.x;
  if (gid >= NB*32) return;
  int b_ = gid >> 5, d = gid & 31;
  float acc = b[d];
  #pragma unroll
  for (int k=0;k<64;k++) acc += qstar[b_*64+k]*w[k*32+d];
  ge[gid] = acc;
}
__global__ void k_pred(const float* __restrict__ ge, const float* __restrict__ w,
                       const float* __restrict__ b, float* __restrict__ pred){
  int b_ = blockIdx.x*blockDim.x + threadIdx.x;
  if (b_ >= NB) return;
  float acc = b[0];
  #pragma unroll
  for (int d=0; d<32; d++) acc += ge[b_*32+d]*w[d];
  pred[b_] = acc;
}

extern "C" void kernel_launch(void* const* d_in, const int* in_sizes, int n_in,
                              void* d_out, int out_size, void* d_ws, size_t ws_size,
                              hipStream_t stream)
{
  const float* x        = (const float*)d_in[0];
  const float* ea       = (const float*)d_in[1];
  const float* lin0_w   = (const float*)d_in[2];
  const float* lin0_b   = (const float*)d_in[3];
  const float* nn1_w    = (const float*)d_in[4];
  const float* nn1_b    = (const float*)d_in[5];
  const float* nn2_w    = (const float*)d_in[6];
  const float* nn2_b    = (const float*)d_in[7];
  const float* root_w   = (const float*)d_in[8];
  const float* conv_b   = (const float*)d_in[9];
  const float* gru_wih  = (const float*)d_in[10];
  const float* gru_whh  = (const float*)d_in[11];
  const float* gru_bih  = (const float*)d_in[12];
  const float* gru_bhh  = (const float*)d_in[13];
  const float* lin1_w   = (const float*)d_in[14];
  const float* lin1_b   = (const float*)d_in[15];
  const float* lstm_wih = (const float*)d_in[16];
  const float* lstm_whh = (const float*)d_in[17];
  const float* lstm_bih = (const float*)d_in[18];
  const float* lstm_bhh = (const float*)d_in[19];
  const float* lin2_w   = (const float*)d_in[20];
  const float* lin2_b   = (const float*)d_in[21];
  const float* lin3_w   = (const float*)d_in[22];
  const float* lin3_b   = (const float*)d_in[23];
  const int*   eidx     = (const int*)d_in[24];
  const int*   batch    = (const int*)d_in[25];
  const int* src = eidx;
  const int* dst = eidx + NE;

  float* out  = (float*)d_out;
  float* pred = out;                 // [128]
  float* gemb = out + NB;            // [128,32]
  float* nemb = out + NB + NB*32;    // [N,32]

  float* ws = (float*)d_ws;
  size_t off = 0;
  auto alloc = [&](size_t nelem){ float* p = ws + off; off += (nelem + 63) & ~(size_t)63; return p; };
  float*  state = alloc((size_t)NN*32);
  float*  agg   = alloc((size_t)NN*32);
  float*  e_buf = alloc(NN);
  int*    startb= (int*)alloc(256);
  ushort* w2c   = (ushort*)alloc(65536);   // 131072 bf16 = 256 KB fragment-packed W2
  float*  zblk  = ws + off;                // zero-initialized region below
  float*  deg   = alloc(NN);
  int*    cnt   = (int*)alloc(NB);
  float*  qstar = alloc(NB*64);
  float*  hs0   = alloc(NB*32);
  float*  hs1   = alloc(NB*32);
  float*  cs    = alloc(NB*32);
  size_t zbytes = (size_t)((ws + off) - zblk) * sizeof(float);

  hipMemsetAsync(zblk, 0, zbytes, stream);

  k_deg<<<(NE+255)/256, 256, 0, stream>>>(dst, deg);
  k_cnt<<<(NN+255)/256, 256, 0, stream>>>(batch, cnt);
  k_scan<<<1, 64, 0, stream>>>(cnt, startb);
  k_init_state<<<(NN*32)/256, 256, 0, stream>>>(x, lin0_w, lin0_b, state);
  k_w2c<<<512, 256, 0, stream>>>(nn2_w, w2c);

  const int nblk = (NE + BM - 1) / BM;     // 1563
  for (int it=0; it<3; ++it){
    hipMemsetAsync(agg, 0, (size_t)NN*32*sizeof(float), stream);
    k_fused<<<nblk, 256, 0, stream>>>(ea, nn1_w, nn1_b, w2c, state, src, dst, agg);
    k_node<<<(NN*32)/256, 256, 0, stream>>>(state, agg, deg, root_w, conv_b,
                                            gru_wih, gru_whh, gru_bih, gru_bhh);
  }
  k_embed<<<(NN*32)/256, 256, 0, stream>>>(state, lin1_w, lin1_b, nemb);

  float* hbuf[2] = {hs0, hs1};
  for (int t=0; t<3; ++t){
    float* hin  = hbuf[t & 1];
    float* hout = hbuf[1 - (t & 1)];
    k_lstm<<<(NB*32)/256, 256, 0, stream>>>(qstar, hin, hout, cs,
                                            lstm_wih, lstm_whh, lstm_bih, lstm_bhh);
    k_attn<<<NB, 256, 0, stream>>>(nemb, hout, startb, e_buf, qstar);
  }
  k_graph<<<(NB*32)/256, 256, 0, stream>>>(qstar, lin2_w, lin2_b, gemb);
  k_pred<<<1, NB, 0, stream>>>(gemb, lin3_w, lin3_b, pred);
}

// Round 8
// 906.840 us; speedup vs baseline: 3.6654x; 1.3396x over previous
//
#include <hip/hip_runtime.h>
#include <float.h>
#include <math.h>

#define NN 50000     // nodes
#define NE 200000    // edges
#define NB 128       // graphs
#define BM 128       // edges per fused-message block

typedef short bf16x8 __attribute__((ext_vector_type(8)));
typedef float f32x4  __attribute__((ext_vector_type(4)));

__device__ __forceinline__ float sgm(float x){ return 1.0f/(1.0f+expf(-x)); }

__device__ __forceinline__ ushort f2bf(float f){   // RNE float->bf16 bits
  unsigned u = __float_as_uint(f);
  return (ushort)((u + 0x7FFFu + ((u >> 16) & 1u)) >> 16);
}
__device__ __forceinline__ float bf2f(ushort s){
  return __uint_as_float(((unsigned)s) << 16);
}

// ---------------- degree / batch counts ----------------
__global__ void k_deg(const int* __restrict__ dst, float* __restrict__ deg){
  int e = blockIdx.x*blockDim.x + threadIdx.x;
  if (e < NE) atomicAdd(&deg[dst[e]], 1.0f);
}
__global__ void k_cnt(const int* __restrict__ batch, int* __restrict__ cnt){
  int n = blockIdx.x*blockDim.x + threadIdx.x;
  if (n < NN) atomicAdd(&cnt[batch[n]], 1);
}
__global__ void k_scan(const int* __restrict__ cnt, int* __restrict__ startb){
  if (threadIdx.x==0 && blockIdx.x==0){
    int s=0;
    for (int b=0;b<NB;b++){ startb[b]=s; s+=cnt[b]; }
    startb[NB]=s;
  }
}

// ---------------- state init: relu(x @ lin0_w + b) ----------------
__global__ void k_init_state(const float* __restrict__ x, const float* __restrict__ w,
                             const float* __restrict__ b, float* __restrict__ state){
  int gid = blockIdx.x*blockDim.x + threadIdx.x;
  if (gid >= NN*32) return;
  int j = gid & 31;
  float xv = x[gid];
  float acc = b[j];
  #pragma unroll
  for (int h=0;h<32;h++) acc += __shfl(xv, h, 32) * w[h*32+j];
  state[gid] = fmaxf(acc, 0.0f);
}

// ---- one-time B-fragment pack: w2c[((k*2+n)*64+l)*8+j] = bf16(W2[k][h*32+o]),
//      h = (l>>4)*8+j, o = n*16+(l&15)  (lane-linear 16B loads in k_fused) ----
__global__ void k_w2c(const float* __restrict__ w2, ushort* __restrict__ w2c){
  int gid = blockIdx.x*256 + threadIdx.x;     // 131072
  if (gid >= 131072) return;
  int j = gid & 7, l = (gid >> 3) & 63, n = (gid >> 9) & 1, k = gid >> 10;
  int h = (l >> 4)*8 + j, o = n*16 + (l & 15);
  w2c[gid] = f2bf(w2[(size_t)k*1024 + h*32 + o]);
}

// -------- fused NNConv message: agg[dst[e]][o] += sum_{k,h} a_e[k]*x_src[e][h]*W2[k][h*32+o]
__global__ __launch_bounds__(256) void k_fused(
    const float* __restrict__ ea, const float* __restrict__ w1, const float* __restrict__ b1,
    const ushort* __restrict__ w2c, const float* __restrict__ state,
    const int* __restrict__ src, const int* __restrict__ dst,
    float* __restrict__ agg)
{
  __shared__ __align__(16) ushort aT[128][136];   // [k][e_local] bf16, pad 8
  __shared__ __align__(16) float  xs[128][36];    // [e_local][h] f32, pad 4
  __shared__ float s_w1[384], s_b1[128], s_ea[384];
  __shared__ int   s_src[128], s_dst[128];

  const int t   = threadIdx.x;
  const int e00 = blockIdx.x * BM;
  const int mv  = min(BM, NE - e00);

  // ---- phase 1: stage small inputs ----
  for (int i=t; i<384; i+=256) s_w1[i] = w1[i];
  if (t < 128) s_b1[t] = b1[t];
  for (int i=t; i<384; i+=256) s_ea[i] = (i < mv*3) ? ea[(size_t)e00*3 + i] : 0.0f;
  if (t < 128){
    bool v = t < mv;
    s_src[t] = v ? src[e00 + t] : 0;
    s_dst[t] = v ? dst[e00 + t] : 0;
  }
  __syncthreads();

  // ---- phase 2a: gather x_src (invalid edges -> 0) ----
  #pragma unroll
  for (int i=0; i<4; ++i){
    int idx = t + i*256;            // 0..1023 : 128 edges x 8 float4
    int el = idx >> 3, ch = idx & 7;
    float4 v = make_float4(0.f,0.f,0.f,0.f);
    if (el < mv) v = *(const float4*)&state[(size_t)s_src[el]*32 + ch*4];
    *(float4*)&xs[el][ch*4] = v;
  }
  // ---- phase 2b: a-gen: aT[k][e] = bf16(relu(ea[e]@W1 + b1)[k]) ----
  {
    int k = t & 127, half = t >> 7;
    float w0 = s_w1[k], w1_ = s_w1[128+k], w2_ = s_w1[256+k], bb = s_b1[k];
    #pragma unroll
    for (int e8=0; e8<8; ++e8){
      bf16x8 pk;
      #pragma unroll
      for (int jj=0; jj<8; ++jj){
        int el = half*64 + e8*8 + jj;
        float v = bb + s_ea[el*3]*w0 + s_ea[el*3+1]*w1_ + s_ea[el*3+2]*w2_;
        pk[jj] = (short)f2bf(fmaxf(v, 0.0f));
      }
      *(bf16x8*)&aT[k][half*64 + e8*8] = pk;
    }
  }
  __syncthreads();

  // ---- phase 3: K-loop (128 k-values), 4 MFMA/k/wave ----
  const int w    = t >> 6;
  const int lane = t & 63;
  const int l15  = lane & 15, l4 = lane >> 4;
  float xf[2][8];
  #pragma unroll
  for (int m=0; m<2; ++m)
    #pragma unroll
    for (int j=0; j<8; ++j) xf[m][j] = xs[w*32 + m*16 + l15][l4*8 + j];

  f32x4 acc[2][2];
  #pragma unroll
  for (int m=0; m<2; ++m)
    #pragma unroll
    for (int n=0; n<2; ++n) acc[m][n] = (f32x4){0.f,0.f,0.f,0.f};

  #pragma unroll 4
  for (int k=0; k<128; ++k){
    float a0 = bf2f(aT[k][w*32 + l15]);        // broadcast reads (conflict-free)
    float a1 = bf2f(aT[k][w*32 + 16 + l15]);
    bf16x8 b0 = *(const bf16x8*)&w2c[((size_t)k*128 + lane)*8];       // L2-hot, coalesced
    bf16x8 b1 = *(const bf16x8*)&w2c[((size_t)k*128 + 64 + lane)*8];
    bf16x8 a0f, a1f;
    #pragma unroll
    for (int p=0; p<4; ++p){                   // round-half-up bf16 pack
      unsigned u0 = __float_as_uint(a0*xf[0][2*p])   + 0x8000u;
      unsigned u1 = __float_as_uint(a0*xf[0][2*p+1]) + 0x8000u;
      ((unsigned*)&a0f)[p] = (u1 & 0xFFFF0000u) | (u0 >> 16);
      unsigned v0 = __float_as_uint(a1*xf[1][2*p])   + 0x8000u;
      unsigned v1 = __float_as_uint(a1*xf[1][2*p+1]) + 0x8000u;
      ((unsigned*)&a1f)[p] = (v1 & 0xFFFF0000u) | (v0 >> 16);
    }
    acc[0][0] = __builtin_amdgcn_mfma_f32_16x16x32_bf16(a0f, b0, acc[0][0], 0,0,0);
    acc[0][1] = __builtin_amdgcn_mfma_f32_16x16x32_bf16(a0f, b1, acc[0][1], 0,0,0);
    acc[1][0] = __builtin_amdgcn_mfma_f32_16x16x32_bf16(a1f, b0, acc[1][0], 0,0,0);
    acc[1][1] = __builtin_amdgcn_mfma_f32_16x16x32_bf16(a1f, b1, acc[1][1], 0,0,0);
  }

  // ---- epilogue: scatter (C/D: col=l&15, row=(l>>4)*4+r — verified) ----
  #pragma unroll
  for (int m=0; m<2; ++m)
    #pragma unroll
    for (int n=0; n<2; ++n)
      #pragma unroll
      for (int r=0; r<4; ++r){
        int el = w*32 + m*16 + l4*4 + r;
        if (e00 + el < NE)
          atomicAdd(&agg[(size_t)s_dst[el]*32 + n*16 + l15], acc[m][n][r]);
      }
}

// ---------------- NNConv epilogue + GRU step (state == out == h) ----------------
__global__ __launch_bounds__(256) void k_node(
    float* __restrict__ state, const float* __restrict__ agg, const float* __restrict__ deg,
    const float* __restrict__ root_w, const float* __restrict__ conv_b,
    const float* __restrict__ wih, const float* __restrict__ whh,
    const float* __restrict__ bih, const float* __restrict__ bhh)
{
  __shared__ float s_root[1024], s_wih[3072], s_whh[3072];
  int t = threadIdx.x;
  for (int i=t;i<1024;i+=256) s_root[i] = root_w[i];
  for (int i=t;i<3072;i+=256){ s_wih[i]=wih[i]; s_whh[i]=whh[i]; }
  __syncthreads();
  int gid = blockIdx.x*256 + t;
  if (gid >= NN*32) return;
  int n = gid >> 5, j = gid & 31;
  float hv = state[gid];
  float dnm = fmaxf(deg[n], 1.0f);
  float acc = conv_b[j] + agg[gid]/dnm;
  #pragma unroll
  for (int h=0;h<32;h++) acc += __shfl(hv,h,32) * s_root[h*32+j];
  float m = fmaxf(acc, 0.0f);
  float xr = bih[j], xz = bih[32+j], xn = bih[64+j];
  #pragma unroll
  for (int h=0;h<32;h++){
    float mh = __shfl(m,h,32);
    xr += mh*s_wih[h*96+j];
    xz += mh*s_wih[h*96+32+j];
    xn += mh*s_wih[h*96+64+j];
  }
  float hr = bhh[j], hz = bhh[32+j], hn = bhh[64+j];
  #pragma unroll
  for (int h=0;h<32;h++){
    float hh2 = __shfl(hv,h,32);
    hr += hh2*s_whh[h*96+j];
    hz += hh2*s_whh[h*96+32+j];
    hn += hh2*s_whh[h*96+64+j];
  }
  float r  = sgm(xr+hr);
  float z  = sgm(xz+hz);
  float nc = tanhf(xn + r*hn);
  state[gid] = (1.0f - z)*nc + z*hv;
}

// ---------------- node_embed = state @ lin1_w + b ----------------
__global__ void k_embed(const float* __restrict__ state, const float* __restrict__ w,
                        const float* __restrict__ b, float* __restrict__ ne){
  int gid = blockIdx.x*blockDim.x + threadIdx.x;
  if (gid >= NN*32) return;
  int j = gid & 31;
  float sv = state[gid];
  float acc = b[j];
  #pragma unroll
  for (int h=0;h<32;h++) acc += __shfl(sv,h,32)*w[h*32+j];
  ne[gid] = acc;
}

// -------- fused Set2Set (3x {LSTM, attention}) + lin2/lin3 head --------
// One block per graph; q_star/h/c live in LDS; weights staged in LDS once.
__global__ __launch_bounds__(256) void k_s2s(
    const float* __restrict__ ne, const int* __restrict__ startb,
    const float* __restrict__ wih, const float* __restrict__ whh,
    const float* __restrict__ bih, const float* __restrict__ bhh,
    const float* __restrict__ lin2_w, const float* __restrict__ lin2_b,
    const float* __restrict__ lin3_w, const float* __restrict__ lin3_b,
    float* __restrict__ e_buf, float* __restrict__ gemb, float* __restrict__ pred)
{
  __shared__ float s_wih[64*128];   // 32 KB  gx = qstar @ wih
  __shared__ float s_whh[32*128];   // 16 KB  gh = h @ whh
  __shared__ float s_l2w[64*32];    // 8 KB
  __shared__ float s_bias[128];     // bih + bhh
  __shared__ float s_l2b[32], s_l3w[32];
  __shared__ float s_qstar[64], s_h[32], s_c[32], s_gates[128], s_ge[32];
  __shared__ float s_red[8][32];
  __shared__ float s_wmax[4];
  __shared__ float s_asum;

  const int b = blockIdx.x;
  const int t = threadIdx.x;
  for (int i=t; i<8192; i+=256) s_wih[i] = wih[i];
  for (int i=t; i<4096; i+=256) s_whh[i] = whh[i];
  for (int i=t; i<2048; i+=256) s_l2w[i] = lin2_w[i];
  if (t < 128) s_bias[t] = bih[t] + bhh[t];
  if (t < 32){ s_l2b[t] = lin2_b[t]; s_l3w[t] = lin3_w[t]; s_h[t]=0.f; s_c[t]=0.f; }
  if (t < 64) s_qstar[t] = 0.f;
  const int s0 = startb[b], s1 = startb[b+1];
  __syncthreads();

  for (int it=0; it<3; ++it){
    // ---- LSTM step: gates from LDS (i,f,g,o) ----
    if (t < 128){
      float g = s_bias[t];
      #pragma unroll
      for (int k=0;k<64;k++) g += s_qstar[k]*s_wih[k*128+t];
      #pragma unroll
      for (int k=0;k<32;k++) g += s_h[k]*s_whh[k*128+t];
      s_gates[t] = g;
    }
    __syncthreads();
    if (t < 32){
      float cn = sgm(s_gates[32+t])*s_c[t] + sgm(s_gates[t])*tanhf(s_gates[64+t]);
      s_c[t] = cn;
      s_h[t] = sgm(s_gates[96+t])*tanhf(cn);
    }
    __syncthreads();
    // ---- attention (same structure as verified k_attn) ----
    int g8 = t >> 5, j = t & 31;
    if (t == 0) s_asum = 0.0f;
    float qv = s_h[j];
    float lmax = -FLT_MAX;
    for (int n = s0 + g8; n < s1; n += 8){
      float p = ne[(size_t)n*32 + j] * qv;
      #pragma unroll
      for (int off=16; off; off>>=1) p += __shfl_xor(p, off, 32);
      if (j == 0) e_buf[n] = p;
      lmax = fmaxf(lmax, p);
    }
    #pragma unroll
    for (int off=32; off; off>>=1) lmax = fmaxf(lmax, __shfl_xor(lmax, off, 64));
    if ((t & 63) == 0) s_wmax[t >> 6] = lmax;
    __syncthreads();   // drains lane-0 e_buf stores; orders s_asum reset vs adds
    float emax = fmaxf(fmaxf(s_wmax[0], s_wmax[1]), fmaxf(s_wmax[2], s_wmax[3]));
    float racc = 0.0f, asum = 0.0f;
    for (int n = s0 + g8; n < s1; n += 8){
      float a = expf(e_buf[n] - emax);
      racc += a * ne[(size_t)n*32 + j];
      if (j == 0) asum += a;
    }
    if (j == 0) atomicAdd(&s_asum, asum);
    s_red[g8][j] = racc;
    __syncthreads();
    if (t < 32){
      float r = 0.0f;
      #pragma unroll
      for (int g2=0; g2<8; g2++) r += s_red[g2][t];
      float as = s_asum;
      if (as == 0.0f) as = 1.0f;
      s_qstar[t]      = s_h[t];
      s_qstar[32 + t] = r / as;
    }
    __syncthreads();
  }
  // ---- head: gemb = qstar@lin2 + b2 ; pred = gemb@lin3 + b3 ----
  if (t < 32){
    float acc = s_l2b[t];
    #pragma unroll
    for (int k=0;k<64;k++) acc += s_qstar[k]*s_l2w[k*32+t];
    gemb[b*32 + t] = acc;
    s_ge[t] = acc;
  }
  __syncthreads();
  if (t == 0){
    float acc = lin3_b[0];
    #pragma unroll
    for (int d=0; d<32; d++) acc += s_ge[d]*s_l3w[d];
    pred[b] = acc;
  }
}

extern "C" void kernel_launch(void* const* d_in, const int* in_sizes, int n_in,
                              void* d_out, int out_size, void* d_ws, size_t ws_size,
                              hipStream_t stream)
{
  const float* x        = (const float*)d_in[0];
  const float* ea       = (const float*)d_in[1];
  const float* lin0_w   = (const float*)d_in[2];
  const float* lin0_b   = (const float*)d_in[3];
  const float* nn1_w    = (const float*)d_in[4];
  const float* nn1_b    = (const float*)d_in[5];
  const float* nn2_w    = (const float*)d_in[6];
  const float* nn2_b    = (const float*)d_in[7];
  const float* root_w   = (const float*)d_in[8];
  const float* conv_b   = (const float*)d_in[9];
  const float* gru_wih  = (const float*)d_in[10];
  const float* gru_whh  = (const float*)d_in[11];
  const float* gru_bih  = (const float*)d_in[12];
  const float* gru_bhh  = (const float*)d_in[13];
  const float* lin1_w   = (const float*)d_in[14];
  const float* lin1_b   = (const float*)d_in[15];
  const float* lstm_wih = (const float*)d_in[16];
  const float* lstm_whh = (const float*)d_in[17];
  const float* lstm_bih = (const float*)d_in[18];
  const float* lstm_bhh = (const float*)d_in[19];
  const float* lin2_w   = (const float*)d_in[20];
  const float* lin2_b   = (const float*)d_in[21];
  const float* lin3_w   = (const float*)d_in[22];
  const float* lin3_b   = (const float*)d_in[23];
  const int*   eidx     = (const int*)d_in[24];
  const int*   batch    = (const int*)d_in[25];
  const int* src = eidx;
  const int* dst = eidx + NE;

  float* out  = (float*)d_out;
  float* pred = out;                 // [128]
  float* gemb = out + NB;            // [128,32]
  float* nemb = out + NB + NB*32;    // [N,32]

  float* ws = (float*)d_ws;
  size_t off = 0;
  auto alloc = [&](size_t nelem){ float* p = ws + off; off += (nelem + 63) & ~(size_t)63; return p; };
  float*  state = alloc((size_t)NN*32);
  float*  agg   = alloc((size_t)NN*32);
  float*  e_buf = alloc(NN);
  int*    startb= (int*)alloc(256);
  ushort* w2c   = (ushort*)alloc(65536);   // 131072 bf16 fragment-packed W2
  float*  zblk  = ws + off;                // zero-initialized region below
  float*  deg   = alloc(NN);
  int*    cnt   = (int*)alloc(NB);
  size_t zbytes = (size_t)((ws + off) - zblk) * sizeof(float);

  hipMemsetAsync(zblk, 0, zbytes, stream);

  k_deg<<<(NE+255)/256, 256, 0, stream>>>(dst, deg);
  k_cnt<<<(NN+255)/256, 256, 0, stream>>>(batch, cnt);
  k_scan<<<1, 64, 0, stream>>>(cnt, startb);
  k_init_state<<<(NN*32)/256, 256, 0, stream>>>(x, lin0_w, lin0_b, state);
  k_w2c<<<512, 256, 0, stream>>>(nn2_w, w2c);

  const int nblk = (NE + BM - 1) / BM;     // 1563
  for (int it=0; it<3; ++it){
    hipMemsetAsync(agg, 0, (size_t)NN*32*sizeof(float), stream);
    k_fused<<<nblk, 256, 0, stream>>>(ea, nn1_w, nn1_b, w2c, state, src, dst, agg);
    k_node<<<(NN*32)/256, 256, 0, stream>>>(state, agg, deg, root_w, conv_b,
                                            gru_wih, gru_whh, gru_bih, gru_bhh);
  }
  k_embed<<<(NN*32)/256, 256, 0, stream>>>(state, lin1_w, lin1_b, nemb);

  k_s2s<<<NB, 256, 0, stream>>>(nemb, startb, lstm_wih, lstm_whh, lstm_bih, lstm_bhh,
                                lin2_w, lin2_b, lin3_w, lin3_b, e_buf, gemb, pred);
}

// Round 10
// 833.174 us; speedup vs baseline: 3.9894x; 1.0884x over previous
//
#include <hip/hip_runtime.h>
#include <float.h>
#include <math.h>

#define NN 50000     // nodes
#define NE 200000    // edges
#define NB 128       // graphs
#define BM 128       // edges per fused-message block

typedef short bf16x8 __attribute__((ext_vector_type(8)));
typedef float f32x4  __attribute__((ext_vector_type(4)));

__device__ __forceinline__ float sgm(float x){ return 1.0f/(1.0f+expf(-x)); }

__device__ __forceinline__ ushort f2bf(float f){   // RNE float->bf16 bits
  unsigned u = __float_as_uint(f);
  return (ushort)((u + 0x7FFFu + ((u >> 16) & 1u)) >> 16);
}
__device__ __forceinline__ float bf2f(ushort s){
  return __uint_as_float(((unsigned)s) << 16);
}

// ---------------- degree / batch counts ----------------
__global__ void k_deg(const int* __restrict__ dst, float* __restrict__ deg){
  int e = blockIdx.x*blockDim.x + threadIdx.x;
  if (e < NE) atomicAdd(&deg[dst[e]], 1.0f);
}
__global__ void k_cnt(const int* __restrict__ batch, int* __restrict__ cnt){
  int n = blockIdx.x*blockDim.x + threadIdx.x;
  if (n < NN) atomicAdd(&cnt[batch[n]], 1);
}
__global__ void k_scan(const int* __restrict__ cnt, int* __restrict__ startb){
  if (threadIdx.x==0 && blockIdx.x==0){
    int s=0;
    for (int b=0;b<NB;b++){ startb[b]=s; s+=cnt[b]; }
    startb[NB]=s;
  }
}

// ---------------- state init: relu(x @ lin0_w + b) ----------------
__global__ void k_init_state(const float* __restrict__ x, const float* __restrict__ w,
                             const float* __restrict__ b, float* __restrict__ state){
  int gid = blockIdx.x*blockDim.x + threadIdx.x;
  if (gid >= NN*32) return;
  int j = gid & 31;
  float xv = x[gid];
  float acc = b[j];
  #pragma unroll
  for (int h=0;h<32;h++) acc += __shfl(xv, h, 32) * w[h*32+j];
  state[gid] = fmaxf(acc, 0.0f);
}

// ---- one-time B-fragment pack: w2c[((k*2+n)*64+l)*8+j] = bf16(W2[k][h*32+o]),
//      h = (l>>4)*8+j, o = n*16+(l&15) ----
__global__ void k_w2c(const float* __restrict__ w2, ushort* __restrict__ w2c){
  int gid = blockIdx.x*256 + threadIdx.x;     // 131072
  if (gid >= 131072) return;
  int j = gid & 7, l = (gid >> 3) & 63, n = (gid >> 9) & 1, k = gid >> 10;
  int h = (l >> 4)*8 + j, o = n*16 + (l & 15);
  w2c[gid] = f2bf(w2[(size_t)k*1024 + h*32 + o]);
}

// -------- fused NNConv message: agg[dst[e]][o] += sum_{k,h} a_e[k]*x_src[e][h]*W2[k][h*32+o]
__global__ __launch_bounds__(256) void k_fused(
    const float* __restrict__ ea, const float* __restrict__ w1, const float* __restrict__ b1,
    const ushort* __restrict__ w2c, const float* __restrict__ state,
    const int* __restrict__ src, const int* __restrict__ dst,
    float* __restrict__ agg)
{
  __shared__ __align__(16) ushort aT[128][136];   // [k][e_local] bf16, pad 8
  __shared__ float s_w1[384], s_b1[128], s_ea[384];
  __shared__ int   s_src[128], s_dst[128];

  const int t   = threadIdx.x;
  const int e00 = blockIdx.x * BM;
  const int mv  = min(BM, NE - e00);

  // ---- phase 1: stage small inputs ----
  for (int i=t; i<384; i+=256) s_w1[i] = w1[i];
  if (t < 128) s_b1[t] = b1[t];
  for (int i=t; i<384; i+=256) s_ea[i] = (i < mv*3) ? ea[(size_t)e00*3 + i] : 0.0f;
  if (t < 128){
    bool v = t < mv;
    s_src[t] = v ? src[e00 + t] : 0;
    s_dst[t] = v ? dst[e00 + t] : 0;
  }
  __syncthreads();

  // ---- per-lane x fragments straight from global (L3-hot); latency hides under a-gen ----
  const int w    = t >> 6;
  const int lane = t & 63;
  const int l15  = lane & 15, l4 = lane >> 4;
  float xf[2][8];
  #pragma unroll
  for (int m=0; m<2; ++m){
    int el = w*32 + m*16 + l15;
    const float* xp = &state[(size_t)s_src[el]*32 + l4*8];
    float4 v0 = *(const float4*)xp;
    float4 v1 = *(const float4*)(xp + 4);
    xf[m][0]=v0.x; xf[m][1]=v0.y; xf[m][2]=v0.z; xf[m][3]=v0.w;
    xf[m][4]=v1.x; xf[m][5]=v1.y; xf[m][6]=v1.z; xf[m][7]=v1.w;
  }

  // ---- a-gen: aT[k][e] = bf16(relu(ea[e]@W1 + b1)[k]) ----
  {
    int k = t & 127, half = t >> 7;
    float w0 = s_w1[k], w1_ = s_w1[128+k], w2_ = s_w1[256+k], bb = s_b1[k];
    #pragma unroll
    for (int e8=0; e8<8; ++e8){
      bf16x8 pk;
      #pragma unroll
      for (int jj=0; jj<8; ++jj){
        int el = half*64 + e8*8 + jj;
        float v = bb + s_ea[el*3]*w0 + s_ea[el*3+1]*w1_ + s_ea[el*3+2]*w2_;
        pk[jj] = (short)f2bf(fmaxf(v, 0.0f));
      }
      *(bf16x8*)&aT[k][half*64 + e8*8] = pk;
    }
  }
  __syncthreads();

  // ---- K-loop (128 k-values), 4 MFMA/k/wave; A generated via v_cvt_pk_bf16_f32 ----
  f32x4 acc[2][2];
  #pragma unroll
  for (int m=0; m<2; ++m)
    #pragma unroll
    for (int n=0; n<2; ++n) acc[m][n] = (f32x4){0.f,0.f,0.f,0.f};

  #pragma unroll 4
  for (int k=0; k<128; ++k){
    float a0 = bf2f(aT[k][w*32 + l15]);        // broadcast reads (conflict-free)
    float a1 = bf2f(aT[k][w*32 + 16 + l15]);
    bf16x8 b0 = *(const bf16x8*)&w2c[((size_t)k*128 + lane)*8];       // L2-hot, coalesced
    bf16x8 b1 = *(const bf16x8*)&w2c[((size_t)k*128 + 64 + lane)*8];
    bf16x8 a0f, a1f;
    #pragma unroll
    for (int p=0; p<4; ++p){
      unsigned r0, r1;
      asm("v_cvt_pk_bf16_f32 %0, %1, %2"
          : "=v"(r0) : "v"(a0*xf[0][2*p]), "v"(a0*xf[0][2*p+1]));
      asm("v_cvt_pk_bf16_f32 %0, %1, %2"
          : "=v"(r1) : "v"(a1*xf[1][2*p]), "v"(a1*xf[1][2*p+1]));
      ((unsigned*)&a0f)[p] = r0;
      ((unsigned*)&a1f)[p] = r1;
    }
    acc[0][0] = __builtin_amdgcn_mfma_f32_16x16x32_bf16(a0f, b0, acc[0][0], 0,0,0);
    acc[0][1] = __builtin_amdgcn_mfma_f32_16x16x32_bf16(a0f, b1, acc[0][1], 0,0,0);
    acc[1][0] = __builtin_amdgcn_mfma_f32_16x16x32_bf16(a1f, b0, acc[1][0], 0,0,0);
    acc[1][1] = __builtin_amdgcn_mfma_f32_16x16x32_bf16(a1f, b1, acc[1][1], 0,0,0);
  }

  // ---- epilogue: scatter (C/D: col=l&15, row=(l>>4)*4+r — verified) ----
  #pragma unroll
  for (int m=0; m<2; ++m)
    #pragma unroll
    for (int n=0; n<2; ++n)
      #pragma unroll
      for (int r=0; r<4; ++r){
        int el = w*32 + m*16 + l4*4 + r;
        if (e00 + el < NE)
          atomicAdd(&agg[(size_t)s_dst[el]*32 + n*16 + l15], acc[m][n][r]);
      }
}

// ------- NNConv epilogue + GRU step; optional fused node_embed on last iter -------
__global__ __launch_bounds__(256) void k_node(
    float* __restrict__ state, const float* __restrict__ agg, const float* __restrict__ deg,
    const float* __restrict__ root_w, const float* __restrict__ conv_b,
    const float* __restrict__ wih, const float* __restrict__ whh,
    const float* __restrict__ bih, const float* __restrict__ bhh,
    const float* __restrict__ lin1_w, const float* __restrict__ lin1_b,
    float* __restrict__ ne, int do_embed)
{
  __shared__ float s_root[1024], s_wih[3072], s_whh[3072], s_lin1[1024], s_l1b[32];
  int t = threadIdx.x;
  for (int i=t;i<1024;i+=256) s_root[i] = root_w[i];
  for (int i=t;i<3072;i+=256){ s_wih[i]=wih[i]; s_whh[i]=whh[i]; }
  if (do_embed){
    for (int i=t;i<1024;i+=256) s_lin1[i] = lin1_w[i];
    if (t < 32) s_l1b[t] = lin1_b[t];
  }
  __syncthreads();
  int gid = blockIdx.x*256 + t;
  if (gid >= NN*32) return;
  int n = gid >> 5, j = gid & 31;
  float hv = state[gid];
  float dnm = fmaxf(deg[n], 1.0f);
  float acc = conv_b[j] + agg[gid]/dnm;
  #pragma unroll
  for (int h=0;h<32;h++) acc += __shfl(hv,h,32) * s_root[h*32+j];
  float m = fmaxf(acc, 0.0f);
  float xr = bih[j], xz = bih[32+j], xn = bih[64+j];
  #pragma unroll
  for (int h=0;h<32;h++){
    float mh = __shfl(m,h,32);
    xr += mh*s_wih[h*96+j];
    xz += mh*s_wih[h*96+32+j];
    xn += mh*s_wih[h*96+64+j];
  }
  float hr = bhh[j], hz = bhh[32+j], hn = bhh[64+j];
  #pragma unroll
  for (int h=0;h<32;h++){
    float hh2 = __shfl(hv,h,32);
    hr += hh2*s_whh[h*96+j];
    hz += hh2*s_whh[h*96+32+j];
    hn += hh2*s_whh[h*96+64+j];
  }
  float r  = sgm(xr+hr);
  float z  = sgm(xz+hz);
  float nc = tanhf(xn + r*hn);
  float hnew = (1.0f - z)*nc + z*hv;
  state[gid] = hnew;
  if (do_embed){
    float acc2 = s_l1b[j];
    #pragma unroll
    for (int h=0;h<32;h++) acc2 += __shfl(hnew,h,32)*s_lin1[h*32+j];
    ne[gid] = acc2;
  }
}

// -------- fused Set2Set (3x {LSTM, attention}) + lin2/lin3 head --------
__global__ __launch_bounds__(256) void k_s2s(
    const float* __restrict__ ne, const int* __restrict__ startb,
    const float* __restrict__ wih, const float* __restrict__ whh,
    const float* __restrict__ bih, const float* __restrict__ bhh,
    const float* __restrict__ lin2_w, const float* __restrict__ lin2_b,
    const float* __restrict__ lin3_w, const float* __restrict__ lin3_b,
    float* __restrict__ e_buf, float* __restrict__ gemb, float* __restrict__ pred)
{
  __shared__ float s_wih[64*128];   // 32 KB
  __shared__ float s_whh[32*128];   // 16 KB
  __shared__ float s_l2w[64*32];    // 8 KB
  __shared__ float s_bias[128];
  __shared__ float s_l2b[32], s_l3w[32];
  __shared__ float s_qstar[64], s_h[32], s_c[32], s_gates[128], s_ge[32];
  __shared__ float s_red[8][32];
  __shared__ float s_wmax[4];
  __shared__ float s_asum;

  const int b = blockIdx.x;
  const int t = threadIdx.x;
  for (int i=t; i<8192; i+=256) s_wih[i] = wih[i];
  for (int i=t; i<4096; i+=256) s_whh[i] = whh[i];
  for (int i=t; i<2048; i+=256) s_l2w[i] = lin2_w[i];
  if (t < 128) s_bias[t] = bih[t] + bhh[t];
  if (t < 32){ s_l2b[t] = lin2_b[t]; s_l3w[t] = lin3_w[t]; s_h[t]=0.f; s_c[t]=0.f; }
  if (t < 64) s_qstar[t] = 0.f;
  const int s0 = startb[b], s1 = startb[b+1];
  __syncthreads();

  for (int it=0; it<3; ++it){
    if (t < 128){
      float g = s_bias[t];
      #pragma unroll
      for (int k=0;k<64;k++) g += s_qstar[k]*s_wih[k*128+t];
      #pragma unroll
      for (int k=0;k<32;k++) g += s_h[k]*s_whh[k*128+t];
      s_gates[t] = g;
    }
    __syncthreads();
    if (t < 32){
      float cn = sgm(s_gates[32+t])*s_c[t] + sgm(s_gates[t])*tanhf(s_gates[64+t]);
      s_c[t] = cn;
      s_h[t] = sgm(s_gates[96+t])*tanhf(cn);
    }
    __syncthreads();
    int g8 = t >> 5, j = t & 31;
    if (t == 0) s_asum = 0.0f;
    float qv = s_h[j];
    float lmax = -FLT_MAX;
    for (int n = s0 + g8; n < s1; n += 8){
      float p = ne[(size_t)n*32 + j] * qv;
      #pragma unroll
      for (int off=16; off; off>>=1) p += __shfl_xor(p, off, 32);
      if (j == 0) e_buf[n] = p;
      lmax = fmaxf(lmax, p);
    }
    #pragma unroll
    for (int off=32; off; off>>=1) lmax = fmaxf(lmax, __shfl_xor(lmax, off, 64));
    if ((t & 63) == 0) s_wmax[t >> 6] = lmax;
    __syncthreads();
    float emax = fmaxf(fmaxf(s_wmax[0], s_wmax[1]), fmaxf(s_wmax[2], s_wmax[3]));
    float racc = 0.0f, asum = 0.0f;
    for (int n = s0 + g8; n < s1; n += 8){
      float a = expf(e_buf[n] - emax);
      racc += a * ne[(size_t)n*32 + j];
      if (j == 0) asum += a;
    }
    if (j == 0) atomicAdd(&s_asum, asum);
    s_red[g8][j] = racc;
    __syncthreads();
    if (t < 32){
      float r = 0.0f;
      #pragma unroll
      for (int g2=0; g2<8; g2++) r += s_red[g2][t];
      float as = s_asum;
      if (as == 0.0f) as = 1.0f;
      s_qstar[t]      = s_h[t];
      s_qstar[32 + t] = r / as;
    }
    __syncthreads();
  }
  if (t < 32){
    float acc = s_l2b[t];
    #pragma unroll
    for (int k=0;k<64;k++) acc += s_qstar[k]*s_l2w[k*32+t];
    gemb[b*32 + t] = acc;
    s_ge[t] = acc;
  }
  __syncthreads();
  if (t == 0){
    float acc = lin3_b[0];
    #pragma unroll
    for (int d=0; d<32; d++) acc += s_ge[d]*s_l3w[d];
    pred[b] = acc;
  }
}

extern "C" void kernel_launch(void* const* d_in, const int* in_sizes, int n_in,
                              void* d_out, int out_size, void* d_ws, size_t ws_size,
                              hipStream_t stream)
{
  const float* x        = (const float*)d_in[0];
  const float* ea       = (const float*)d_in[1];
  const float* lin0_w   = (const float*)d_in[2];
  const float* lin0_b   = (const float*)d_in[3];
  const float* nn1_w    = (const float*)d_in[4];
  const float* nn1_b    = (const float*)d_in[5];
  const float* nn2_w    = (const float*)d_in[6];
  const float* nn2_b    = (const float*)d_in[7];
  const float* root_w   = (const float*)d_in[8];
  const float* conv_b   = (const float*)d_in[9];
  const float* gru_wih  = (const float*)d_in[10];
  const float* gru_whh  = (const float*)d_in[11];
  const float* gru_bih  = (const float*)d_in[12];
  const float* gru_bhh  = (const float*)d_in[13];
  const float* lin1_w   = (const float*)d_in[14];
  const float* lin1_b   = (const float*)d_in[15];
  const float* lstm_wih = (const float*)d_in[16];
  const float* lstm_whh = (const float*)d_in[17];
  const float* lstm_bih = (const float*)d_in[18];
  const float* lstm_bhh = (const float*)d_in[19];
  const float* lin2_w   = (const float*)d_in[20];
  const float* lin2_b   = (const float*)d_in[21];
  const float* lin3_w   = (const float*)d_in[22];
  const float* lin3_b   = (const float*)d_in[23];
  const int*   eidx     = (const int*)d_in[24];
  const int*   batch    = (const int*)d_in[25];
  const int* src = eidx;
  const int* dst = eidx + NE;

  float* out  = (float*)d_out;
  float* pred = out;                 // [128]
  float* gemb = out + NB;            // [128,32]
  float* nemb = out + NB + NB*32;    // [N,32]

  float* ws = (float*)d_ws;
  size_t off = 0;
  auto alloc = [&](size_t nelem){ float* p = ws + off; off += (nelem + 63) & ~(size_t)63; return p; };
  float*  state = alloc((size_t)NN*32);
  float*  agg   = alloc((size_t)NN*32);
  float*  e_buf = alloc(NN);
  int*    startb= (int*)alloc(256);
  ushort* w2c   = (ushort*)alloc(65536);   // 131072 bf16 fragment-packed W2
  float*  zblk  = ws + off;                // zero-initialized region below
  float*  deg   = alloc(NN);
  int*    cnt   = (int*)alloc(NB);
  size_t zbytes = (size_t)((ws + off) - zblk) * sizeof(float);

  hipMemsetAsync(zblk, 0, zbytes, stream);

  k_deg<<<(NE+255)/256, 256, 0, stream>>>(dst, deg);
  k_cnt<<<(NN+255)/256, 256, 0, stream>>>(batch, cnt);
  k_scan<<<1, 64, 0, stream>>>(cnt, startb);
  k_init_state<<<(NN*32)/256, 256, 0, stream>>>(x, lin0_w, lin0_b, state);
  k_w2c<<<512, 256, 0, stream>>>(nn2_w, w2c);

  const int nblk = (NE + BM - 1) / BM;     // 1563
  for (int it=0; it<3; ++it){
    hipMemsetAsync(agg, 0, (size_t)NN*32*sizeof(float), stream);
    k_fused<<<nblk, 256, 0, stream>>>(ea, nn1_w, nn1_b, w2c, state, src, dst, agg);
    k_node<<<(NN*32)/256, 256, 0, stream>>>(state, agg, deg, root_w, conv_b,
                                            gru_wih, gru_whh, gru_bih, gru_bhh,
                                            lin1_w, lin1_b, nemb, (it==2) ? 1 : 0);
  }

  k_s2s<<<NB, 256, 0, stream>>>(nemb, startb, lstm_wih, lstm_whh, lstm_bih, lstm_bhh,
                                lin2_w, lin2_b, lin3_w, lin3_b, e_buf, gemb, pred);
}

// Round 12
// 714.296 us; speedup vs baseline: 4.6534x; 1.1664x over previous
//
#include <hip/hip_runtime.h>
#include <float.h>
#include <math.h>

#define NN 50000     // nodes
#define NE 200000    // edges
#define NB 128       // graphs
#define BM 128       // edges per fused-message block

typedef short bf16x8 __attribute__((ext_vector_type(8)));
typedef float f32x4  __attribute__((ext_vector_type(4)));

__device__ __forceinline__ float sgm(float x){ return 1.0f/(1.0f+expf(-x)); }

__device__ __forceinline__ ushort f2bf(float f){   // RNE float->bf16 bits
  unsigned u = __float_as_uint(f);
  return (ushort)((u + 0x7FFFu + ((u >> 16) & 1u)) >> 16);
}
__device__ __forceinline__ float bf2f(ushort s){
  return __uint_as_float(((unsigned)s) << 16);
}

// ---------------- degree ----------------
__global__ void k_deg(const int* __restrict__ dst, float* __restrict__ deg){
  int e = blockIdx.x*blockDim.x + threadIdx.x;
  if (e < NE) atomicAdd(&deg[dst[e]], 1.0f);
}

// ---- segment starts from SORTED batch via boundary detection (no atomics) ----
__global__ void k_bounds(const int* __restrict__ batch, int* __restrict__ startb){
  int n = blockIdx.x*blockDim.x + threadIdx.x;
  if (n >= NN) return;
  int b  = batch[n];
  int bp = (n == 0) ? -1 : batch[n-1];
  for (int q = bp+1; q <= b; ++q) startb[q] = n;
  if (n == NN-1){
    for (int q = b+1; q <= NB; ++q) startb[q] = NN;
  }
}

// ---------------- state init: relu(x @ lin0_w + b) ----------------
__global__ void k_init_state(const float* __restrict__ x, const float* __restrict__ w,
                             const float* __restrict__ b, float* __restrict__ state){
  int gid = blockIdx.x*blockDim.x + threadIdx.x;
  if (gid >= NN*32) return;
  int j = gid & 31;
  float xv = x[gid];
  float acc = b[j];
  #pragma unroll
  for (int h=0;h<32;h++) acc += __shfl(xv, h, 32) * w[h*32+j];
  state[gid] = fmaxf(acc, 0.0f);
}

// ---- one-time B-fragment pack: w2c[((k*2+n)*64+l)*8+j] = bf16(W2[k][h*32+o]),
//      h = (l>>4)*8+j, o = n*16+(l&15) ----
__global__ void k_w2c(const float* __restrict__ w2, ushort* __restrict__ w2c){
  int gid = blockIdx.x*256 + threadIdx.x;     // 131072
  if (gid >= 131072) return;
  int j = gid & 7, l = (gid >> 3) & 63, n = (gid >> 9) & 1, k = gid >> 10;
  int h = (l >> 4)*8 + j, o = n*16 + (l & 15);
  w2c[gid] = f2bf(w2[(size_t)k*1024 + h*32 + o]);
}

// -------- fused NNConv message: agg[dst[e]][o] += sum_{k,h} a_e[k]*x_src[e][h]*W2[k][h*32+o]
__global__ __launch_bounds__(256) void k_fused(
    const float* __restrict__ ea, const float* __restrict__ w1, const float* __restrict__ b1,
    const ushort* __restrict__ w2c, const float* __restrict__ state,
    const int* __restrict__ src, const int* __restrict__ dst,
    float* __restrict__ agg)
{
  __shared__ __align__(16) ushort aT[128][136];   // [k][e_local] bf16, pad 8
  __shared__ float s_w1[384], s_b1[128], s_ea[384];
  __shared__ int   s_src[128], s_dst[128];

  const int t   = threadIdx.x;
  const int e00 = blockIdx.x * BM;
  const int mv  = min(BM, NE - e00);

  // ---- phase 1: stage small inputs ----
  for (int i=t; i<384; i+=256) s_w1[i] = w1[i];
  if (t < 128) s_b1[t] = b1[t];
  for (int i=t; i<384; i+=256) s_ea[i] = (i < mv*3) ? ea[(size_t)e00*3 + i] : 0.0f;
  if (t < 128){
    bool v = t < mv;
    s_src[t] = v ? src[e00 + t] : 0;
    s_dst[t] = v ? dst[e00 + t] : 0;
  }
  __syncthreads();

  // ---- per-lane x fragments straight from global (L3-hot); latency hides under a-gen ----
  const int w    = t >> 6;
  const int lane = t & 63;
  const int l15  = lane & 15, l4 = lane >> 4;
  float xf[2][8];
  #pragma unroll
  for (int m=0; m<2; ++m){
    int el = w*32 + m*16 + l15;
    const float* xp = &state[(size_t)s_src[el]*32 + l4*8];
    float4 v0 = *(const float4*)xp;
    float4 v1 = *(const float4*)(xp + 4);
    xf[m][0]=v0.x; xf[m][1]=v0.y; xf[m][2]=v0.z; xf[m][3]=v0.w;
    xf[m][4]=v1.x; xf[m][5]=v1.y; xf[m][6]=v1.z; xf[m][7]=v1.w;
  }

  // ---- a-gen: aT[k][e] = bf16(relu(ea[e]@W1 + b1)[k]) ----
  {
    int k = t & 127, half = t >> 7;
    float w0 = s_w1[k], w1_ = s_w1[128+k], w2_ = s_w1[256+k], bb = s_b1[k];
    #pragma unroll
    for (int e8=0; e8<8; ++e8){
      bf16x8 pk;
      #pragma unroll
      for (int jj=0; jj<8; ++jj){
        int el = half*64 + e8*8 + jj;
        float v = bb + s_ea[el*3]*w0 + s_ea[el*3+1]*w1_ + s_ea[el*3+2]*w2_;
        pk[jj] = (short)f2bf(fmaxf(v, 0.0f));
      }
      *(bf16x8*)&aT[k][half*64 + e8*8] = pk;
    }
  }
  __syncthreads();

  // ---- K-loop (128 k-values), 4 MFMA/k/wave; A generated via v_cvt_pk_bf16_f32 ----
  f32x4 acc[2][2];
  #pragma unroll
  for (int m=0; m<2; ++m)
    #pragma unroll
    for (int n=0; n<2; ++n) acc[m][n] = (f32x4){0.f,0.f,0.f,0.f};

  #pragma unroll 4
  for (int k=0; k<128; ++k){
    float a0 = bf2f(aT[k][w*32 + l15]);        // broadcast reads (conflict-free)
    float a1 = bf2f(aT[k][w*32 + 16 + l15]);
    bf16x8 b0 = *(const bf16x8*)&w2c[((size_t)k*128 + lane)*8];       // L2-hot, coalesced
    bf16x8 b1 = *(const bf16x8*)&w2c[((size_t)k*128 + 64 + lane)*8];
    bf16x8 a0f, a1f;
    #pragma unroll
    for (int p=0; p<4; ++p){
      unsigned r0, r1;
      asm("v_cvt_pk_bf16_f32 %0, %1, %2"
          : "=v"(r0) : "v"(a0*xf[0][2*p]), "v"(a0*xf[0][2*p+1]));
      asm("v_cvt_pk_bf16_f32 %0, %1, %2"
          : "=v"(r1) : "v"(a1*xf[1][2*p]), "v"(a1*xf[1][2*p+1]));
      ((unsigned*)&a0f)[p] = r0;
      ((unsigned*)&a1f)[p] = r1;
    }
    acc[0][0] = __builtin_amdgcn_mfma_f32_16x16x32_bf16(a0f, b0, acc[0][0], 0,0,0);
    acc[0][1] = __builtin_amdgcn_mfma_f32_16x16x32_bf16(a0f, b1, acc[0][1], 0,0,0);
    acc[1][0] = __builtin_amdgcn_mfma_f32_16x16x32_bf16(a1f, b0, acc[1][0], 0,0,0);
    acc[1][1] = __builtin_amdgcn_mfma_f32_16x16x32_bf16(a1f, b1, acc[1][1], 0,0,0);
  }

  // ---- epilogue: scatter (C/D: col=l&15, row=(l>>4)*4+r — verified) ----
  #pragma unroll
  for (int m=0; m<2; ++m)
    #pragma unroll
    for (int n=0; n<2; ++n)
      #pragma unroll
      for (int r=0; r<4; ++r){
        int el = w*32 + m*16 + l4*4 + r;
        if (e00 + el < NE)
          atomicAdd(&agg[(size_t)s_dst[el]*32 + n*16 + l15], acc[m][n][r]);
      }
}

// ------- NNConv epilogue + GRU step; optional fused node_embed on last iter -------
__global__ __launch_bounds__(256) void k_node(
    float* __restrict__ state, const float* __restrict__ agg, const float* __restrict__ deg,
    const float* __restrict__ root_w, const float* __restrict__ conv_b,
    const float* __restrict__ wih, const float* __restrict__ whh,
    const float* __restrict__ bih, const float* __restrict__ bhh,
    const float* __restrict__ lin1_w, const float* __restrict__ lin1_b,
    float* __restrict__ ne, int do_embed)
{
  __shared__ float s_root[1024], s_wih[3072], s_whh[3072], s_lin1[1024], s_l1b[32];
  int t = threadIdx.x;
  for (int i=t;i<1024;i+=256) s_root[i] = root_w[i];
  for (int i=t;i<3072;i+=256){ s_wih[i]=wih[i]; s_whh[i]=whh[i]; }
  if (do_embed){
    for (int i=t;i<1024;i+=256) s_lin1[i] = lin1_w[i];
    if (t < 32) s_l1b[t] = lin1_b[t];
  }
  __syncthreads();
  int gid = blockIdx.x*256 + t;
  if (gid >= NN*32) return;
  int n = gid >> 5, j = gid & 31;
  float hv = state[gid];
  float dnm = fmaxf(deg[n], 1.0f);
  float acc = conv_b[j] + agg[gid]/dnm;
  #pragma unroll
  for (int h=0;h<32;h++) acc += __shfl(hv,h,32) * s_root[h*32+j];
  float m = fmaxf(acc, 0.0f);
  float xr = bih[j], xz = bih[32+j], xn = bih[64+j];
  #pragma unroll
  for (int h=0;h<32;h++){
    float mh = __shfl(m,h,32);
    xr += mh*s_wih[h*96+j];
    xz += mh*s_wih[h*96+32+j];
    xn += mh*s_wih[h*96+64+j];
  }
  float hr = bhh[j], hz = bhh[32+j], hn = bhh[64+j];
  #pragma unroll
  for (int h=0;h<32;h++){
    float hh2 = __shfl(hv,h,32);
    hr += hh2*s_whh[h*96+j];
    hz += hh2*s_whh[h*96+32+j];
    hn += hh2*s_whh[h*96+64+j];
  }
  float r  = sgm(xr+hr);
  float z  = sgm(xz+hz);
  float nc = tanhf(xn + r*hn);
  float hnew = (1.0f - z)*nc + z*hv;
  state[gid] = hnew;
  if (do_embed){
    float acc2 = s_l1b[j];
    #pragma unroll
    for (int h=0;h<32;h++) acc2 += __shfl(hnew,h,32)*s_lin1[h*32+j];
    ne[gid] = acc2;
  }
}

// -------- fused Set2Set (3x {LSTM, attention}) + lin2/lin3 head --------
__global__ __launch_bounds__(256) void k_s2s(
    const float* __restrict__ ne, const int* __restrict__ startb,
    const float* __restrict__ wih, const float* __restrict__ whh,
    const float* __restrict__ bih, const float* __restrict__ bhh,
    const float* __restrict__ lin2_w, const float* __restrict__ lin2_b,
    const float* __restrict__ lin3_w, const float* __restrict__ lin3_b,
    float* __restrict__ e_buf, float* __restrict__ gemb, float* __restrict__ pred)
{
  __shared__ float s_wih[64*128];   // 32 KB
  __shared__ float s_whh[32*128];   // 16 KB
  __shared__ float s_l2w[64*32];    // 8 KB
  __shared__ float s_bias[128];
  __shared__ float s_l2b[32], s_l3w[32];
  __shared__ float s_qstar[64], s_h[32], s_c[32], s_gates[128], s_ge[32];
  __shared__ float s_red[8][32];
  __shared__ float s_wmax[4];
  __shared__ float s_asum;

  const int b = blockIdx.x;
  const int t = threadIdx.x;
  for (int i=t; i<8192; i+=256) s_wih[i] = wih[i];
  for (int i=t; i<4096; i+=256) s_whh[i] = whh[i];
  for (int i=t; i<2048; i+=256) s_l2w[i] = lin2_w[i];
  if (t < 128) s_bias[t] = bih[t] + bhh[t];
  if (t < 32){ s_l2b[t] = lin2_b[t]; s_l3w[t] = lin3_w[t]; s_h[t]=0.f; s_c[t]=0.f; }
  if (t < 64) s_qstar[t] = 0.f;
  const int s0 = startb[b], s1 = startb[b+1];
  __syncthreads();

  for (int it=0; it<3; ++it){
    if (t < 128){
      float g = s_bias[t];
      #pragma unroll
      for (int k=0;k<64;k++) g += s_qstar[k]*s_wih[k*128+t];
      #pragma unroll
      for (int k=0;k<32;k++) g += s_h[k]*s_whh[k*128+t];
      s_gates[t] = g;
    }
    __syncthreads();
    if (t < 32){
      float cn = sgm(s_gates[32+t])*s_c[t] + sgm(s_gates[t])*tanhf(s_gates[64+t]);
      s_c[t] = cn;
      s_h[t] = sgm(s_gates[96+t])*tanhf(cn);
    }
    __syncthreads();
    int g8 = t >> 5, j = t & 31;
    if (t == 0) s_asum = 0.0f;
    float qv = s_h[j];
    float lmax = -FLT_MAX;
    for (int n = s0 + g8; n < s1; n += 8){
      float p = ne[(size_t)n*32 + j] * qv;
      #pragma unroll
      for (int off=16; off; off>>=1) p += __shfl_xor(p, off, 32);
      if (j == 0) e_buf[n] = p;
      lmax = fmaxf(lmax, p);
    }
    #pragma unroll
    for (int off=32; off; off>>=1) lmax = fmaxf(lmax, __shfl_xor(lmax, off, 64));
    if ((t & 63) == 0) s_wmax[t >> 6] = lmax;
    __syncthreads();
    float emax = fmaxf(fmaxf(s_wmax[0], s_wmax[1]), fmaxf(s_wmax[2], s_wmax[3]));
    float racc = 0.0f, asum = 0.0f;
    for (int n = s0 + g8; n < s1; n += 8){
      float a = expf(e_buf[n] - emax);
      racc += a * ne[(size_t)n*32 + j];
      if (j == 0) asum += a;
    }
    if (j == 0) atomicAdd(&s_asum, asum);
    s_red[g8][j] = racc;
    __syncthreads();
    if (t < 32){
      float r = 0.0f;
      #pragma unroll
      for (int g2=0; g2<8; g2++) r += s_red[g2][t];
      float as = s_asum;
      if (as == 0.0f) as = 1.0f;
      s_qstar[t]      = s_h[t];
      s_qstar[32 + t] = r / as;
    }
    __syncthreads();
  }
  if (t < 32){
    float acc = s_l2b[t];
    #pragma unroll
    for (int k=0;k<64;k++) acc += s_qstar[k]*s_l2w[k*32+t];
    gemb[b*32 + t] = acc;
    s_ge[t] = acc;
  }
  __syncthreads();
  if (t == 0){
    float acc = lin3_b[0];
    #pragma unroll
    for (int d=0; d<32; d++) acc += s_ge[d]*s_l3w[d];
    pred[b] = acc;
  }
}

extern "C" void kernel_launch(void* const* d_in, const int* in_sizes, int n_in,
                              void* d_out, int out_size, void* d_ws, size_t ws_size,
                              hipStream_t stream)
{
  const float* x        = (const float*)d_in[0];
  const float* ea       = (const float*)d_in[1];
  const float* lin0_w   = (const float*)d_in[2];
  const float* lin0_b   = (const float*)d_in[3];
  const float* nn1_w    = (const float*)d_in[4];
  const float* nn1_b    = (const float*)d_in[5];
  const float* nn2_w    = (const float*)d_in[6];
  const float* nn2_b    = (const float*)d_in[7];
  const float* root_w   = (const float*)d_in[8];
  const float* conv_b   = (const float*)d_in[9];
  const float* gru_wih  = (const float*)d_in[10];
  const float* gru_whh  = (const float*)d_in[11];
  const float* gru_bih  = (const float*)d_in[12];
  const float* gru_bhh  = (const float*)d_in[13];
  const float* lin1_w   = (const float*)d_in[14];
  const float* lin1_b   = (const float*)d_in[15];
  const float* lstm_wih = (const float*)d_in[16];
  const float* lstm_whh = (const float*)d_in[17];
  const float* lstm_bih = (const float*)d_in[18];
  const float* lstm_bhh = (const float*)d_in[19];
  const float* lin2_w   = (const float*)d_in[20];
  const float* lin2_b   = (const float*)d_in[21];
  const float* lin3_w   = (const float*)d_in[22];
  const float* lin3_b   = (const float*)d_in[23];
  const int*   eidx     = (const int*)d_in[24];
  const int*   batch    = (const int*)d_in[25];
  const int* src = eidx;
  const int* dst = eidx + NE;

  float* out  = (float*)d_out;
  float* pred = out;                 // [128]
  float* gemb = out + NB;            // [128,32]
  float* nemb = out + NB + NB*32;    // [N,32]

  float* ws = (float*)d_ws;
  size_t off = 0;
  auto alloc = [&](size_t nelem){ float* p = ws + off; off += (nelem + 63) & ~(size_t)63; return p; };
  float*  state = alloc((size_t)NN*32);
  float*  agg   = alloc((size_t)NN*32);
  float*  e_buf = alloc(NN);
  int*    startb= (int*)alloc(256);
  ushort* w2c   = (ushort*)alloc(65536);   // 131072 bf16 fragment-packed W2
  float*  zblk  = ws + off;                // zero-initialized region below
  float*  deg   = alloc(NN);
  size_t zbytes = (size_t)((ws + off) - zblk) * sizeof(float);

  hipMemsetAsync(zblk, 0, zbytes, stream);

  k_deg<<<(NE+255)/256, 256, 0, stream>>>(dst, deg);
  k_bounds<<<(NN+255)/256, 256, 0, stream>>>(batch, startb);
  k_init_state<<<(NN*32)/256, 256, 0, stream>>>(x, lin0_w, lin0_b, state);
  k_w2c<<<512, 256, 0, stream>>>(nn2_w, w2c);

  const int nblk = (NE + BM - 1) / BM;     // 1563
  for (int it=0; it<3; ++it){
    hipMemsetAsync(agg, 0, (size_t)NN*32*sizeof(float), stream);
    k_fused<<<nblk, 256, 0, stream>>>(ea, nn1_w, nn1_b, w2c, state, src, dst, agg);
    k_node<<<(NN*32)/256, 256, 0, stream>>>(state, agg, deg, root_w, conv_b,
                                            gru_wih, gru_whh, gru_bih, gru_bhh,
                                            lin1_w, lin1_b, nemb, (it==2) ? 1 : 0);
  }

  k_s2s<<<NB, 256, 0, stream>>>(nemb, startb, lstm_wih, lstm_whh, lstm_bih, lstm_bhh,
                                lin2_w, lin2_b, lin3_w, lin3_b, e_buf, gemb, pred);
}